// Round 9
// baseline (205.391 us; speedup 1.0000x reference)
//
#include <hip/hip_runtime.h>
#include <hip/hip_bf16.h>

typedef __hip_bfloat16 bf16;
typedef _Float16 f16;
typedef __attribute__((ext_vector_type(8))) __bf16 bf16x8;
typedef __attribute__((ext_vector_type(8))) _Float16 f16x8;
typedef __attribute__((ext_vector_type(4))) _Float16 f16x4;
typedef __attribute__((ext_vector_type(4))) float floatx4;
typedef __attribute__((ext_vector_type(16))) float floatx16;

#define T_SEQ 2048
#define EMB   1024
#define LAMBDA_INIT 0.35550906759096926f

// round-to-nearest-even fp32 -> bf16
__device__ __forceinline__ bf16 f2bf(float f) {
  unsigned u;
  __builtin_memcpy(&u, &f, 4);
  u += 0x7FFF + ((u >> 16) & 1);
  unsigned short h = (unsigned short)(u >> 16);
  bf16 r;
  __builtin_memcpy(&r, &h, 2);
  return r;
}

// v_cvt_pk_bf16_f32: d[15:0]=bf16(lo), d[31:16]=bf16(hi)
__device__ __forceinline__ int cvtpk_bf16(float lo, float hi) {
  int r;
  asm("v_cvt_pk_bf16_f32 %0, %1, %2" : "=v"(r) : "v"(lo), "v"(hi));
  return r;
}

// v_permlane32_swap_b32: swaps a's upper-32-lane half with b's lower half.
__device__ __forceinline__ void permswap(int& a, int& b) {
  asm volatile("v_permlane32_swap_b32 %0, %1" : "+v"(a), "+v"(b));
}

__device__ __forceinline__ void gl_lds16(const void* g, void* l) {
  __builtin_amdgcn_global_load_lds((const __attribute__((address_space(1))) void*)g,
                                   (__attribute__((address_space(3))) void*)l, 16, 0, 0);
}

__device__ __forceinline__ floatx4 mfma_h(f16x8 a, f16x8 b, floatx4 c) {
  return __builtin_amdgcn_mfma_f32_16x16x32_f16(a, b, c, 0, 0, 0);
}
__device__ __forceinline__ floatx16 mfma32_h(f16x8 a, f16x8 b, floatx16 c) {
  return __builtin_amdgcn_mfma_f32_32x32x16_f16(a, b, c, 0, 0, 0);
}
__device__ __forceinline__ floatx16 mfma32_bf(bf16x8 a, bf16x8 b, floatx16 c) {
  return __builtin_amdgcn_mfma_f32_32x32x16_bf16(a, b, c, 0, 0, 0);
}

// =====================================================================
// fp32 -> fp16 conversion for x, Wq, Wk, Wv, Wo.
// =====================================================================
__global__ __launch_bounds__(256) void convert_kernel(
    const float* __restrict__ x,  const float* __restrict__ wq,
    const float* __restrict__ wk, const float* __restrict__ wv,
    const float* __restrict__ wo,
    f16* __restrict__ xf, f16* __restrict__ wqf, f16* __restrict__ wkf,
    f16* __restrict__ wvf, f16* __restrict__ wof)
{
  int b = blockIdx.x;
  const float* src; f16* dst; long off;
  if      (b < 2048) { src = x;  dst = xf;  off = (long)b * 1024; }
  else if (b < 3072) { src = wq; dst = wqf; off = (long)(b - 2048) * 1024; }
  else if (b < 4096) { src = wk; dst = wkf; off = (long)(b - 3072) * 1024; }
  else if (b < 5120) { src = wv; dst = wvf; off = (long)(b - 4096) * 1024; }
  else               { src = wo; dst = wof; off = (long)(b - 5120) * 1024; }
  long i = off + threadIdx.x * 4;
  float4 v = *(const float4*)(src + i);
  f16x4 o;
  o.x = (f16)v.x; o.y = (f16)v.y; o.z = (f16)v.z; o.w = (f16)v.w;
  *(f16x4*)(dst + i) = o;
}

// =====================================================================
// DIRECT fp16 NT GEMM, 64x128 tile — no LDS staging, no loop barriers.
// Rationale (round-8 PMC): qkv inputs total 10MB = L2/L3-resident; the
// LDS path (gl_lds + vmcnt(0) drain + 2 barriers + ds_reads per K-step)
// is pure overhead AND forbids compiler software-pipelining across
// K-steps (MfmaUtil 7.9%). Each MFMA fragment is a clean 16B/lane read
// of the row-major NT operand: lane l reads row (l&15), k-chunk (l>>4)
// -> lanes {q,16+q,32+q,48+q} cover 64B contiguous: one a-load touches
// exactly 16 full cache lines, zero waste. Waves fully independent; the
// compiler hoists iter-i+1 loads above iter-i MFMAs freely (G7).
// LDS: 16KB epilogue store-coalescing buffer only.
// MODE 2 = RoPE-Q epilogue (fold 0.125) -> fp16; MODE 3 = RoPE-K (inv)
// MODE 0 = bf16 out (V).
// =====================================================================
template <int MODE>
__device__ __forceinline__ void gemm64x128_direct(
    const f16* __restrict__ A_, const f16* __restrict__ B_,
    void* C0v, int Kld, int Klen, int ldc, int m0, int n0, char* smem)
{
  const int tid  = threadIdx.x;
  const int wave = tid >> 6, lane = tid & 63, quad = lane >> 4, l16 = lane & 15;
  const int mo = (wave & 1) << 5;
  const int no = (wave >> 1) << 6;

  floatx4 acc[2][4];
  #pragma unroll
  for (int i = 0; i < 2; i++)
    #pragma unroll
    for (int j = 0; j < 4; j++) { acc[i][j][0]=0.f; acc[i][j][1]=0.f; acc[i][j][2]=0.f; acc[i][j][3]=0.f; }

  // fragment base pointers (16x16x32 A/B layout: row=lane&15, k=(lane>>4)*8+j)
  const f16* a0p = A_ + (long)(m0 + mo + l16) * Kld + quad * 8;
  const f16* a1p = a0p + (long)16 * Kld;
  const f16* b0p = B_ + (long)(n0 + no + l16) * Kld + quad * 8;
  const f16* b1p = b0p + (long)16 * Kld;
  const f16* b2p = b0p + (long)32 * Kld;
  const f16* b3p = b0p + (long)48 * Kld;

  #pragma unroll 4
  for (int k0 = 0; k0 < Klen; k0 += 32) {
    f16x8 a0 = *(const f16x8*)(a0p + k0);
    f16x8 a1 = *(const f16x8*)(a1p + k0);
    f16x8 b0 = *(const f16x8*)(b0p + k0);
    f16x8 b1 = *(const f16x8*)(b1p + k0);
    f16x8 b2 = *(const f16x8*)(b2p + k0);
    f16x8 b3 = *(const f16x8*)(b3p + k0);
    acc[0][0] = mfma_h(a0, b0, acc[0][0]);
    acc[0][1] = mfma_h(a0, b1, acc[0][1]);
    acc[0][2] = mfma_h(a0, b2, acc[0][2]);
    acc[0][3] = mfma_h(a0, b3, acc[0][3]);
    acc[1][0] = mfma_h(a1, b0, acc[1][0]);
    acc[1][1] = mfma_h(a1, b1, acc[1][1]);
    acc[1][2] = mfma_h(a1, b2, acc[1][2]);
    acc[1][3] = mfma_h(a1, b3, acc[1][3]);
  }

  unsigned short* E = (unsigned short*)smem;   // 64x128 2-byte = 16 KB
  #pragma unroll
  for (int i = 0; i < 2; i++)
    #pragma unroll
    for (int j = 0; j < 4; j++)
      #pragma unroll
      for (int r = 0; r < 4; r++) {
        int row = mo + i * 16 + quad * 4 + r;
        int col = no + j * 16 + l16;
        float v = acc[i][j][r];
        unsigned short bits;
        if (MODE == 0) {
          bf16 t = f2bf(v);
          __builtin_memcpy(&bits, &t, 2);
        } else {
          float p = __shfl_xor(v, 1, 64);
          int d = col & 63;
          float fr = (float)(m0 + row) * __expf((float)(d >> 1) * -0.28782313662425574f);
          float sn, cs;
          sincosf(fr, &sn, &cs);
          float rot = (col & 1) ? fmaf(v, cs, p * sn) : fmaf(v, cs, -p * sn);
          float power = (float)(m0 + row - 1024) * (1.0f / 512.0f);
          if (MODE == 3) power = -power;
          float sv = fmaf(2.0f, (float)(d & 31), 25.6f) * (1.0f / 89.6f);
          float s = __expf(power * __logf(sv));
          float ov = rot * s;
          if (MODE == 2) ov *= 0.125f;
          f16 t = (f16)ov;
          __builtin_memcpy(&bits, &t, 2);
        }
        E[row * 128 + col] = bits;
      }
  __syncthreads();
  const int rr0 = tid >> 4;
  const int c8  = (tid & 15) * 8;
  #pragma unroll
  for (int p2 = 0; p2 < 4; p2++) {
    int row = p2 * 16 + rr0;
    *(uint4*)((unsigned short*)C0v + (long)(m0 + row) * ldc + n0 + c8) =
        *(const uint4*)(E + row * 128 + c8);
  }
}

// =====================================================================
// LDS-staged fp16 NT GEMM (round-8 single-barrier dbuf) — kept for
// out_gemm only (MODE 1), doubling as a same-run A/B comparator
// against the direct core above.
// =====================================================================
template <int MODE>
__device__ __forceinline__ void gemm64x128_f16(
    const f16* __restrict__ A_, const f16* __restrict__ B_,
    void* C0v, int Kld, int Klen, int ldc, int m0, int n0, char* smem)
{
  const int tid  = threadIdx.x;
  const int wave = tid >> 6, lane = tid & 63, quad = lane >> 4, l16 = lane & 15;
  const int mo = (wave & 1) << 5;
  const int no = (wave >> 1) << 6;

  floatx4 acc[2][4];
  #pragma unroll
  for (int i = 0; i < 2; i++)
    #pragma unroll
    for (int j = 0; j < 4; j++) { acc[i][j][0]=0.f; acc[i][j][1]=0.f; acc[i][j][2]=0.f; acc[i][j][3]=0.f; }

  const int srow = tid >> 3;
  const int ch   = (tid & 7) ^ (srow & 7);
  const long aoff = (long)(m0 + srow) * Kld + ch * 8;
  const long boff = (long)(n0 + srow) * Kld + ch * 8;
  const int wb = wave << 10;

  // prologue: stage K-step 0 into buffer 0
  #pragma unroll
  for (int rr = 0; rr < 2; rr++)
    gl_lds16(A_ + aoff + (long)rr * 32 * Kld, smem + wb + rr * 4096);
  #pragma unroll
  for (int rr = 0; rr < 4; rr++)
    gl_lds16(B_ + boff + (long)rr * 32 * Kld, smem + 8192 + wb + rr * 4096);

  for (int k0 = 0; k0 < Klen; k0 += 64) {
    const int cur = (k0 >> 6) & 1;
    const char* sb = smem + cur * 24576;

    asm volatile("s_waitcnt vmcnt(0)" ::: "memory");
    asm volatile("s_barrier" ::: "memory");

    const f16* As = (const f16*)sb;
    const f16* Bs = (const f16*)(sb + 8192);

    f16x8 a[2][2], b[2][4];
    #pragma unroll
    for (int kt = 0; kt < 2; kt++) {
      #pragma unroll
      for (int i = 0; i < 2; i++) {
        int m = mo + i * 16 + l16;
        a[kt][i] = *(const f16x8*)(As + m * 64 + ((((kt << 2) | quad) ^ (m & 7)) << 3));
      }
      #pragma unroll
      for (int j = 0; j < 4; j++) {
        int n = no + j * 16 + l16;
        b[kt][j] = *(const f16x8*)(Bs + n * 64 + ((((kt << 2) | quad) ^ (n & 7)) << 3));
      }
    }

    if (k0 + 64 < Klen) {
      char* nb = smem + (cur ^ 1) * 24576;
      #pragma unroll
      for (int rr = 0; rr < 2; rr++)
        gl_lds16(A_ + aoff + k0 + 64 + (long)rr * 32 * Kld, nb + wb + rr * 4096);
      #pragma unroll
      for (int rr = 0; rr < 4; rr++)
        gl_lds16(B_ + boff + k0 + 64 + (long)rr * 32 * Kld, nb + 8192 + wb + rr * 4096);
    }

    #pragma unroll
    for (int kt = 0; kt < 2; kt++)
      #pragma unroll
      for (int i = 0; i < 2; i++)
        #pragma unroll
        for (int j = 0; j < 4; j++)
          acc[i][j] = mfma_h(a[kt][i], b[kt][j], acc[i][j]);
  }
  __syncthreads();

  if (MODE == 1) {
    #pragma unroll
    for (int i = 0; i < 2; i++)
      #pragma unroll
      for (int j = 0; j < 4; j++)
        #pragma unroll
        for (int r = 0; r < 4; r++) {
          int row = m0 + mo + i * 16 + quad * 4 + r;
          int col = n0 + no + j * 16 + l16;
          ((float*)C0v)[(long)row * ldc + col] = acc[i][j][r];
        }
  }
}

__global__ __launch_bounds__(256) void qkv_gemm(
    const f16* __restrict__ xf,
    const f16* __restrict__ wqf, const f16* __restrict__ wkf,
    const f16* __restrict__ wvf,
    f16* __restrict__ qf, f16* __restrict__ kf, bf16* __restrict__ vt)
{
  __shared__ char smem[16384];
  int bid = blockIdx.x;
  if (bid < 256) {
    gemm64x128_direct<2>(xf, wqf, qf, 1024, 1024, 1024, (bid >> 3) * 64, (bid & 7) * 128, smem);
  } else if (bid < 512) {
    bid -= 256;
    gemm64x128_direct<3>(xf, wkf, kf, 1024, 1024, 1024, (bid >> 3) * 64, (bid & 7) * 128, smem);
  } else {
    bid -= 512;
    gemm64x128_direct<0>(wvf, xf, vt, 1024, 1024, 2048, (bid >> 4) * 64, (bid & 15) * 128, smem);
  }
}

// out_gemm K-split by 2: 512 blocks (2/CU) each accumulate a 64x128 fp32
// partial over half of K; add_out merges.
__global__ __launch_bounds__(256) void out_gemm(const f16* __restrict__ attn,
                                                const f16* __restrict__ Wo,
                                                float* __restrict__ p0,
                                                float* __restrict__ p1)
{
  __shared__ char smem[49152];
  int bid = blockIdx.x;
  const int kh = bid >> 8;       // K-half 0/1
  const int b  = bid & 255;
  float* pb = kh ? p1 : p0;
  gemm64x128_f16<1>(attn + kh * 512, Wo + kh * 512, pb, 1024, 512, 1024,
                    (b >> 3) * 64, (b & 7) * 128, smem);
}

__global__ __launch_bounds__(256) void add_out(const float* __restrict__ p0,
                                               const float* __restrict__ p1,
                                               float* __restrict__ out)
{
  long i = ((long)blockIdx.x * 256 + threadIdx.x) * 4;
  float4 a = *(const float4*)(p0 + i);
  float4 b = *(const float4*)(p1 + i);
  float4 c;
  c.x = a.x + b.x; c.y = a.y + b.y; c.z = a.z + b.z; c.w = a.w + b.w;
  *(float4*)(out + i) = c;
}

// =====================================================================
// Differential flash attention — register-staged single-barrier edition
// (round-5 structure, unchanged; best measured 51.0 µs).
// =====================================================================
__global__ __launch_bounds__(256) void diff_attn(
    const f16* __restrict__ qf_, const f16* __restrict__ kf_,
    const bf16* __restrict__ vt,
    const float* __restrict__ lq1, const float* __restrict__ lk1,
    const float* __restrict__ lq2, const float* __restrict__ lk2,
    f16* __restrict__ attn)
{
  __shared__ char smem[65536];
  // buf b at b*32768: K0 @0 (8KB) | K1 @8192 (8KB) | V @16384 (16KB)
  const int tid  = threadIdx.x;
  const int wave = tid >> 6, lane = tid & 63;
  const int l32 = lane & 31, lh = lane >> 5;
  const int h  = blockIdx.x & 7;         // head pair — XCD-affine
  const int qb = blockIdx.x >> 3;        // q block 0..63 (32 rows each)
  const int hl = wave >> 1;              // head in pair
  const int ws = wave & 1;               // key-half of this wave
  const int hh = h * 2 + hl;
  const int t0 = qb * 32;

  float a1 = lq1[lane] * lk1[lane];
  float a2 = lq2[lane] * lk2[lane];
  #pragma unroll
  for (int off = 1; off < 64; off <<= 1) {
    a1 += __shfl_xor(a1, off, 64);
    a2 += __shfl_xor(a2, off, 64);
  }
  const float lam = __expf(a1) - __expf(a2) + LAMBDA_INIT;

  // Q B-frags (32 rows x 64 d): n=query=l32, k = kt*16 + lh*8 + j
  f16x8 qfr[4];
  {
    const f16* qrow = qf_ + (long)(t0 + l32) * EMB + hh * 64 + lh * 8;
    #pragma unroll
    for (int kt = 0; kt < 4; kt++) qfr[kt] = *(const f16x8*)(qrow + kt * 16);
  }

  floatx16 o[4];   // nt over Dv=128, un-normalized accumulation
  #pragma unroll
  for (int nt = 0; nt < 4; nt++)
    #pragma unroll
    for (int r = 0; r < 16; r++) o[nt][r] = 0.f;
  // denominator partials: 4-way tree to cut the serial add chain
  float lr0 = 0.f, lr1 = 0.f, lr2 = 0.f, lr3 = 0.f;

  // staging: waves 0,1 -> K0,K1; waves 2,3 -> V halves
  const int srow = lane >> 3;
  const int ch   = (lane & 7) ^ srow;
  const f16*  kgp = kf_ + (long)(h * 2 + ws) * 64 + (long)srow * EMB + ch * 8;
  const bf16* vgp = vt + (long)(h * 128 + (wave - 2) * 64 + srow) * T_SEQ + ch * 8;
  const int kofs = wave * 8192;                 // waves 0,1
  const int vofs = 16384 + (wave - 2) * 8192;   // waves 2,3

  // prologue: stage tile 0 into buffer 0
  if (wave < 2) {
    #pragma unroll
    for (int j = 0; j < 8; j++)
      gl_lds16(kgp + (long)j * 8 * EMB, smem + kofs + j * 1024);
  } else {
    #pragma unroll
    for (int j = 0; j < 8; j++)
      gl_lds16(vgp + (long)j * 8 * T_SEQ, smem + vofs + j * 1024);
  }

  for (int kb = 0; kb < T_SEQ; kb += 64) {
    const int cur = (kb >> 6) & 1;
    const char* sb = smem + cur * 32768;

    // own tile-i loads were issued a full iteration ago -> no stall
    asm volatile("s_waitcnt vmcnt(0)" ::: "memory");
    // all waves' tile-i loads landed; all waves left iter i-1
    asm volatile("s_barrier" ::: "memory");

    const f16*  Ks  = (const f16*)(sb + hl * 8192);
    const bf16* Vsb = (const bf16*)(sb + 16384);

    // ---- register staging: ALL ds_reads before any gl_lds issue ----
    f16x8 kfr[4];
    #pragma unroll
    for (int kt = 0; kt < 4; kt++) {
      int krow = ws * 32 + l32;
      int c = kt * 2 + lh;
      kfr[kt] = *(const f16x8*)(Ks + krow * 64 + ((c ^ (krow & 7)) << 3));
    }
    bf16x8 vfr[4][2];
    #pragma unroll
    for (int nt = 0; nt < 4; nt++) {
      #pragma unroll
      for (int kt = 0; kt < 2; kt++) {
        int vrow = nt * 32 + l32;
        int c = ws * 4 + kt * 2 + lh;
        vfr[nt][kt] = *(const bf16x8*)(Vsb + vrow * 64 + ((c ^ (vrow & 7)) << 3));
      }
    }

    // ---- prefetch issue (after all ds_reads in program order) ----
    if (kb + 64 < T_SEQ) {
      char* nb = smem + (cur ^ 1) * 32768;
      if (wave < 2) {
        #pragma unroll
        for (int j = 0; j < 8; j++)
          gl_lds16(kgp + (long)(kb + 64) * EMB + (long)j * 8 * EMB,
                   nb + kofs + j * 1024);
      } else {
        #pragma unroll
        for (int j = 0; j < 8; j++)
          gl_lds16(vgp + (kb + 64) + (long)j * 8 * T_SEQ,
                   nb + vofs + j * 1024);
      }
    }

    // ---- compute: pure registers from here ----
    // QK^T swapped: A=K (m=key=l32 of own half), B=Q (n=query=l32)
    floatx16 s;
    #pragma unroll
    for (int r = 0; r < 16; r++) s[r] = 0.f;
    #pragma unroll
    for (int kt = 0; kt < 4; kt++)
      s = mfma32_h(kfr[kt], qfr[kt], s);
    // static-offset softmax; denominator partials in a 4-way tree
    #pragma unroll
    for (int r = 0; r < 4; r++) {
      float p0 = __builtin_amdgcn_exp2f(
          fmaf(s[r], 1.4426950408889634f, -17.312340490667562f));
      float p1 = __builtin_amdgcn_exp2f(
          fmaf(s[r + 4], 1.4426950408889634f, -17.312340490667562f));
      float p2 = __builtin_amdgcn_exp2f(
          fmaf(s[r + 8], 1.4426950408889634f, -17.312340490667562f));
      float p3 = __builtin_amdgcn_exp2f(
          fmaf(s[r + 12], 1.4426950408889634f, -17.312340490667562f));
      s[r] = p0; s[r + 4] = p1; s[r + 8] = p2; s[r + 12] = p3;
      lr0 += p0; lr1 += p1; lr2 += p2; lr3 += p3;
    }
    // in-register P -> bf16 A-frags (cvt_pk + permlane32_swap)
    bf16x8 pf[2];
    #pragma unroll
    for (int kt = 0; kt < 2; kt++) {
      const int b0 = kt * 8;
      int w0 = cvtpk_bf16(s[b0 + 0], s[b0 + 1]);
      int w1 = cvtpk_bf16(s[b0 + 2], s[b0 + 3]);
      int w2 = cvtpk_bf16(s[b0 + 4], s[b0 + 5]);
      int w3 = cvtpk_bf16(s[b0 + 6], s[b0 + 7]);
      permswap(w0, w2);
      permswap(w1, w3);
      union { int i[4]; bf16x8 v; } u;
      u.i[0] = w0; u.i[1] = w1; u.i[2] = w2; u.i[3] = w3;
      pf[kt] = u.v;
    }
    // PV: O += P V over own keys (register V frags)
    #pragma unroll
    for (int nt = 0; nt < 4; nt++) {
      #pragma unroll
      for (int kt = 0; kt < 2; kt++)
        o[nt] = mfma32_bf(pf[kt], vfr[nt][kt], o[nt]);
    }
  }
  __syncthreads();   // loop exit sync before epilogue overwrites smem

  float lr = (lr0 + lr1) + (lr2 + lr3);
  // merge lh halves: lrw = this wave's full 32-key denominator for query l32
  float lrw = lr + __shfl_xor(lr, 32, 64);

  float* Cb = (float*)smem;                  // 2 heads x 32x128 fp32 = 32KB
  float* Lb = (float*)(smem + 32768);        // 128 denominator partials

  // phase 1: key-half ws==1 publishes raw O; all waves publish lrw
  if (ws == 1) {
    #pragma unroll
    for (int r = 0; r < 16; r++) {
      int m = (r & 3) + 8 * (r >> 2) + 4 * lh;
      #pragma unroll
      for (int nt = 0; nt < 4; nt++)
        Cb[hl * 4096 + m * 128 + nt * 32 + l32] = o[nt][r];
    }
  }
  if (lh == 0) Lb[ws * 64 + hl * 32 + l32] = lrw;
  __syncthreads();
  // phase 2: ws==0 merges halves and normalizes
  if (ws == 0) {
    #pragma unroll
    for (int r = 0; r < 16; r++) {
      int m = (r & 3) + 8 * (r >> 2) + 4 * lh;
      float inv = 1.0f / (Lb[hl * 32 + m] + Lb[64 + hl * 32 + m]);
      #pragma unroll
      for (int nt = 0; nt < 4; nt++)
        o[nt][r] = (o[nt][r] + Cb[hl * 4096 + m * 128 + nt * 32 + l32]) * inv;
    }
  }
  __syncthreads();
  // phase 3: head1 publishes normalized O1
  if (hl == 1 && ws == 0) {
    #pragma unroll
    for (int r = 0; r < 16; r++) {
      int m = (r & 3) + 8 * (r >> 2) + 4 * lh;
      #pragma unroll
      for (int nt = 0; nt < 4; nt++)
        Cb[4096 + m * 128 + nt * 32 + l32] = o[nt][r];
    }
  }
  __syncthreads();
  // phase 4: head0 does diff + rms-norm + store
  if (hl == 0 && ws == 0) {
    float ss[16];
    #pragma unroll
    for (int r = 0; r < 16; r++) {
      int m = (r & 3) + 8 * (r >> 2) + 4 * lh;
      ss[r] = 0.f;
      #pragma unroll
      for (int nt = 0; nt < 4; nt++) {
        float v = o[nt][r] - lam * Cb[4096 + m * 128 + nt * 32 + l32];
        o[nt][r] = v;
        ss[r] += v * v;
      }
    }
    #pragma unroll
    for (int r = 0; r < 16; r++) {
      ss[r] += __shfl_xor(ss[r], 1, 64);
      ss[r] += __shfl_xor(ss[r], 2, 64);
      ss[r] += __shfl_xor(ss[r], 4, 64);
      ss[r] += __shfl_xor(ss[r], 8, 64);
      ss[r] += __shfl_xor(ss[r], 16, 64);
      float rms = rsqrtf(ss[r] * (1.0f / 128.0f) + 1e-5f) * (1.0f - LAMBDA_INIT);
      int m = (r & 3) + 8 * (r >> 2) + 4 * lh;
      #pragma unroll
      for (int nt = 0; nt < 4; nt++)
        attn[(long)(t0 + m) * EMB + h * 128 + nt * 32 + l32] = (f16)(o[nt][r] * rms);
    }
  }
}

// =====================================================================
extern "C" void kernel_launch(void* const* d_in, const int* in_sizes, int n_in,
                              void* d_out, int out_size, void* d_ws, size_t ws_size,
                              hipStream_t stream)
{
  (void)in_sizes; (void)n_in; (void)out_size; (void)ws_size;
  const float* x   = (const float*)d_in[0];
  const float* Wq  = (const float*)d_in[1];
  const float* Wk  = (const float*)d_in[2];
  const float* Wv  = (const float*)d_in[3];
  const float* Wo  = (const float*)d_in[4];
  const float* lq1 = (const float*)d_in[5];
  const float* lk1 = (const float*)d_in[6];
  const float* lq2 = (const float*)d_in[7];
  const float* lk2 = (const float*)d_in[8];
  float* out = (float*)d_out;

  const size_t TM = (size_t)T_SEQ * EMB;  // 2M elems
  const size_t WM = (size_t)EMB * EMB;    // 1M elems
  bf16* vtws = (bf16*)d_ws;          // 4MB      @ 0
  f16*  aws  = (f16*)(vtws + TM);    // 4MB      @ 4MB
  f16*  xf   = aws  + TM;            // 4MB      @ 8MB
  f16*  wqf  = xf   + TM;            // 2MB      @ 12MB
  f16*  wkf  = wqf  + WM;            //          @ 14MB
  f16*  wvf  = wkf  + WM;            //          @ 16MB
  f16*  wof  = wvf  + WM;            //          @ 18MB
  f16*  qf   = wof  + WM;            // 4MB      @ 20MB
  f16*  kf   = qf   + TM;            // 4MB      @ 24MB

  // K-split partials REUSE dead regions (zero extra workspace):
  //  p0 (8MB fp32) over xf+wqf+wkf  — dead after qkv_gemm
  //  p1 (8MB fp32) over qf+kf       — dead after diff_attn
  float* p0 = (float*)xf;
  float* p1 = (float*)qf;

  convert_kernel<<<6144, 256, 0, stream>>>(x, Wq, Wk, Wv, Wo,
                                           xf, wqf, wkf, wvf, wof);
  qkv_gemm<<<768, 256, 0, stream>>>(xf, wqf, wkf, wvf, qf, kf, vtws);
  diff_attn<<<512, 256, 0, stream>>>(qf, kf, vtws, lq1, lk1, lq2, lk2, aws);
  out_gemm<<<512, 256, 0, stream>>>(aws, wof, p0, p1);
  add_out<<<2048, 256, 0, stream>>>(p0, p1, out);
}

// Round 10
// 191.439 us; speedup vs baseline: 1.0729x; 1.0729x over previous
//
#include <hip/hip_runtime.h>
#include <hip/hip_bf16.h>

typedef __hip_bfloat16 bf16;
typedef _Float16 f16;
typedef __attribute__((ext_vector_type(8))) __bf16 bf16x8;
typedef __attribute__((ext_vector_type(8))) _Float16 f16x8;
typedef __attribute__((ext_vector_type(4))) _Float16 f16x4;
typedef __attribute__((ext_vector_type(4))) float floatx4;
typedef __attribute__((ext_vector_type(16))) float floatx16;

#define T_SEQ 2048
#define EMB   1024
#define LAMBDA_INIT 0.35550906759096926f

// round-to-nearest-even fp32 -> bf16
__device__ __forceinline__ bf16 f2bf(float f) {
  unsigned u;
  __builtin_memcpy(&u, &f, 4);
  u += 0x7FFF + ((u >> 16) & 1);
  unsigned short h = (unsigned short)(u >> 16);
  bf16 r;
  __builtin_memcpy(&r, &h, 2);
  return r;
}

// v_cvt_pk_bf16_f32: d[15:0]=bf16(lo), d[31:16]=bf16(hi)
__device__ __forceinline__ int cvtpk_bf16(float lo, float hi) {
  int r;
  asm("v_cvt_pk_bf16_f32 %0, %1, %2" : "=v"(r) : "v"(lo), "v"(hi));
  return r;
}

// v_permlane32_swap_b32: swaps a's upper-32-lane half with b's lower half.
__device__ __forceinline__ void permswap(int& a, int& b) {
  asm volatile("v_permlane32_swap_b32 %0, %1" : "+v"(a), "+v"(b));
}

__device__ __forceinline__ void gl_lds16(const void* g, void* l) {
  __builtin_amdgcn_global_load_lds((const __attribute__((address_space(1))) void*)g,
                                   (__attribute__((address_space(3))) void*)l, 16, 0, 0);
}

__device__ __forceinline__ floatx4 mfma_h(f16x8 a, f16x8 b, floatx4 c) {
  return __builtin_amdgcn_mfma_f32_16x16x32_f16(a, b, c, 0, 0, 0);
}
__device__ __forceinline__ floatx16 mfma32_h(f16x8 a, f16x8 b, floatx16 c) {
  return __builtin_amdgcn_mfma_f32_32x32x16_f16(a, b, c, 0, 0, 0);
}
__device__ __forceinline__ floatx16 mfma32_bf(bf16x8 a, bf16x8 b, floatx16 c) {
  return __builtin_amdgcn_mfma_f32_32x32x16_bf16(a, b, c, 0, 0, 0);
}

// =====================================================================
// fp32 -> fp16 conversion for x, Wq, Wk, Wv, Wo.
// =====================================================================
__global__ __launch_bounds__(256) void convert_kernel(
    const float* __restrict__ x,  const float* __restrict__ wq,
    const float* __restrict__ wk, const float* __restrict__ wv,
    const float* __restrict__ wo,
    f16* __restrict__ xf, f16* __restrict__ wqf, f16* __restrict__ wkf,
    f16* __restrict__ wvf, f16* __restrict__ wof)
{
  int b = blockIdx.x;
  const float* src; f16* dst; long off;
  if      (b < 2048) { src = x;  dst = xf;  off = (long)b * 1024; }
  else if (b < 3072) { src = wq; dst = wqf; off = (long)(b - 2048) * 1024; }
  else if (b < 4096) { src = wk; dst = wkf; off = (long)(b - 3072) * 1024; }
  else if (b < 5120) { src = wv; dst = wvf; off = (long)(b - 4096) * 1024; }
  else               { src = wo; dst = wof; off = (long)(b - 5120) * 1024; }
  long i = off + threadIdx.x * 4;
  float4 v = *(const float4*)(src + i);
  f16x4 o;
  o.x = (f16)v.x; o.y = (f16)v.y; o.z = (f16)v.z; o.w = (f16)v.w;
  *(f16x4*)(dst + i) = o;
}

// =====================================================================
// fp16 NT GEMM, 64x128 tile, BK=64 — TRIPLE-buffered, depth-2 counted
// vmcnt (T3/T4). Round-9 A/B: LDS-staged (59.6us, MfmaUtil 7.9%) beats
// direct-from-L2 (73.4us, 6.8%) — staging is needed; the remaining stall
// was the depth-1 vmcnt(0) exposing L3-miss latency every K-step.
// Per K-step it: vmcnt(6) [tile it+1's 6 loads may stay in flight; tile
// it's have landed] -> s_barrier -> 12x ds_read_b128 -> regs -> issue
// tile it+2 into buf (it+2)%3 [safe: all waves finished reading that
// buffer during iter it-1, before this barrier] -> register-only MFMA.
// LDS: 3 x 24KB = 72KB (2 blocks/CU — same as 48KB rounded; >64KB static
// is legal on gfx950, cf. 128KB 8-phase example).
// Kld = row stride of A/B; Klen = K-extent (K-split support).
// MODE 2 = RoPE-Q epilogue (fold 0.125) -> fp16; MODE 3 = RoPE-K (inv)
// MODE 0 = bf16 out (V);  MODE 1 = fp32 out (output-projection partial)
// =====================================================================
template <int MODE>
__device__ __forceinline__ void gemm64x128_f16(
    const f16* __restrict__ A_, const f16* __restrict__ B_,
    void* C0v, int Kld, int Klen, int ldc, int m0, int n0, char* smem)
{
  const int tid  = threadIdx.x;
  const int wave = tid >> 6, lane = tid & 63, quad = lane >> 4, l16 = lane & 15;
  const int mo = (wave & 1) << 5;
  const int no = (wave >> 1) << 6;

  floatx4 acc[2][4];
  #pragma unroll
  for (int i = 0; i < 2; i++)
    #pragma unroll
    for (int j = 0; j < 4; j++) { acc[i][j][0]=0.f; acc[i][j][1]=0.f; acc[i][j][2]=0.f; acc[i][j][3]=0.f; }

  const int srow = tid >> 3;
  const int ch   = (tid & 7) ^ (srow & 7);
  const long aoff = (long)(m0 + srow) * Kld + ch * 8;
  const long boff = (long)(n0 + srow) * Kld + ch * 8;
  const int wb = wave << 10;

  const int NT = Klen >> 6;

  // prologue: stage K-steps 0 and 1 into buffers 0 and 1 (NT >= 8 always)
  #pragma unroll
  for (int t = 0; t < 2; t++) {
    char* bb = smem + t * 24576;
    #pragma unroll
    for (int rr = 0; rr < 2; rr++)
      gl_lds16(A_ + aoff + t * 64 + (long)rr * 32 * Kld, bb + wb + rr * 4096);
    #pragma unroll
    for (int rr = 0; rr < 4; rr++)
      gl_lds16(B_ + boff + t * 64 + (long)rr * 32 * Kld, bb + 8192 + wb + rr * 4096);
  }

  int cur = 0;   // buffer index = it % 3, maintained by increment-wrap
  for (int it = 0; it < NT; ++it) {
    const char* sb = smem + cur * 24576;

    // counted wait: tile it landed; tile it+1's loads may stay in flight
    if (it + 1 < NT) {
      asm volatile("s_waitcnt vmcnt(6)" ::: "memory");
    } else {
      asm volatile("s_waitcnt vmcnt(0)" ::: "memory");
    }
    asm volatile("s_barrier" ::: "memory");

    const f16* As = (const f16*)sb;
    const f16* Bs = (const f16*)(sb + 8192);

    // ---- register staging: ALL ds_reads before any gl_lds issue ----
    f16x8 a[2][2], b[2][4];
    #pragma unroll
    for (int kt = 0; kt < 2; kt++) {
      #pragma unroll
      for (int i = 0; i < 2; i++) {
        int m = mo + i * 16 + l16;
        a[kt][i] = *(const f16x8*)(As + m * 64 + ((((kt << 2) | quad) ^ (m & 7)) << 3));
      }
      #pragma unroll
      for (int j = 0; j < 4; j++) {
        int n = no + j * 16 + l16;
        b[kt][j] = *(const f16x8*)(Bs + n * 64 + ((((kt << 2) | quad) ^ (n & 7)) << 3));
      }
    }

    // ---- depth-2 prefetch issue: tile it+2 into buf (it+2)%3 ----
    if (it + 2 < NT) {
      int nxt = cur + 2; if (nxt >= 3) nxt -= 3;
      char* nb = smem + nxt * 24576;
      const long kk = (long)(it + 2) * 64;
      #pragma unroll
      for (int rr = 0; rr < 2; rr++)
        gl_lds16(A_ + aoff + kk + (long)rr * 32 * Kld, nb + wb + rr * 4096);
      #pragma unroll
      for (int rr = 0; rr < 4; rr++)
        gl_lds16(B_ + boff + kk + (long)rr * 32 * Kld, nb + 8192 + wb + rr * 4096);
    }

    // ---- register-only MFMA ----
    #pragma unroll
    for (int kt = 0; kt < 2; kt++)
      #pragma unroll
      for (int i = 0; i < 2; i++)
        #pragma unroll
        for (int j = 0; j < 4; j++)
          acc[i][j] = mfma_h(a[kt][i], b[kt][j], acc[i][j]);

    cur = (cur == 2) ? 0 : cur + 1;
  }
  __syncthreads();   // before epilogue reuses smem

  if (MODE == 1) {
    #pragma unroll
    for (int i = 0; i < 2; i++)
      #pragma unroll
      for (int j = 0; j < 4; j++)
        #pragma unroll
        for (int r = 0; r < 4; r++) {
          int row = m0 + mo + i * 16 + quad * 4 + r;
          int col = n0 + no + j * 16 + l16;
          ((float*)C0v)[(long)row * ldc + col] = acc[i][j][r];
        }
  } else {
    unsigned short* E = (unsigned short*)smem;   // 64x128 2-byte = 16 KB
    #pragma unroll
    for (int i = 0; i < 2; i++)
      #pragma unroll
      for (int j = 0; j < 4; j++)
        #pragma unroll
        for (int r = 0; r < 4; r++) {
          int row = mo + i * 16 + quad * 4 + r;
          int col = no + j * 16 + l16;
          float v = acc[i][j][r];
          unsigned short bits;
          if (MODE == 0) {
            bf16 t = f2bf(v);
            __builtin_memcpy(&bits, &t, 2);
          } else {
            float p = __shfl_xor(v, 1, 64);
            int d = col & 63;
            float fr = (float)(m0 + row) * __expf((float)(d >> 1) * -0.28782313662425574f);
            float sn, cs;
            sincosf(fr, &sn, &cs);
            float rot = (col & 1) ? fmaf(v, cs, p * sn) : fmaf(v, cs, -p * sn);
            float power = (float)(m0 + row - 1024) * (1.0f / 512.0f);
            if (MODE == 3) power = -power;
            float sv = fmaf(2.0f, (float)(d & 31), 25.6f) * (1.0f / 89.6f);
            float s = __expf(power * __logf(sv));
            float ov = rot * s;
            if (MODE == 2) ov *= 0.125f;
            f16 t = (f16)ov;
            __builtin_memcpy(&bits, &t, 2);
          }
          E[row * 128 + col] = bits;
        }
    __syncthreads();
    const int rr0 = tid >> 4;
    const int c8  = (tid & 15) * 8;
    #pragma unroll
    for (int p2 = 0; p2 < 4; p2++) {
      int row = p2 * 16 + rr0;
      *(uint4*)((unsigned short*)C0v + (long)(m0 + row) * ldc + n0 + c8) =
          *(const uint4*)(E + row * 128 + c8);
    }
  }
}

__global__ __launch_bounds__(256) void qkv_gemm(
    const f16* __restrict__ xf,
    const f16* __restrict__ wqf, const f16* __restrict__ wkf,
    const f16* __restrict__ wvf,
    f16* __restrict__ qf, f16* __restrict__ kf, bf16* __restrict__ vt)
{
  __shared__ char smem[73728];
  int bid = blockIdx.x;
  if (bid < 256) {
    gemm64x128_f16<2>(xf, wqf, qf, 1024, 1024, 1024, (bid >> 3) * 64, (bid & 7) * 128, smem);
  } else if (bid < 512) {
    bid -= 256;
    gemm64x128_f16<3>(xf, wkf, kf, 1024, 1024, 1024, (bid >> 3) * 64, (bid & 7) * 128, smem);
  } else {
    bid -= 512;
    gemm64x128_f16<0>(wvf, xf, vt, 1024, 1024, 2048, (bid >> 4) * 64, (bid & 15) * 128, smem);
  }
}

// out_gemm K-split by 2: 512 blocks (2/CU) each accumulate a 64x128 fp32
// partial over half of K; add_out merges.
__global__ __launch_bounds__(256) void out_gemm(const f16* __restrict__ attn,
                                                const f16* __restrict__ Wo,
                                                float* __restrict__ p0,
                                                float* __restrict__ p1)
{
  __shared__ char smem[73728];
  int bid = blockIdx.x;
  const int kh = bid >> 8;       // K-half 0/1
  const int b  = bid & 255;
  float* pb = kh ? p1 : p0;
  gemm64x128_f16<1>(attn + kh * 512, Wo + kh * 512, pb, 1024, 512, 1024,
                    (b >> 3) * 64, (b & 7) * 128, smem);
}

__global__ __launch_bounds__(256) void add_out(const float* __restrict__ p0,
                                               const float* __restrict__ p1,
                                               float* __restrict__ out)
{
  long i = ((long)blockIdx.x * 256 + threadIdx.x) * 4;
  float4 a = *(const float4*)(p0 + i);
  float4 b = *(const float4*)(p1 + i);
  float4 c;
  c.x = a.x + b.x; c.y = a.y + b.y; c.z = a.z + b.z; c.w = a.w + b.w;
  *(float4*)(out + i) = c;
}

// =====================================================================
// Differential flash attention — register-staged single-barrier edition
// (round-5 structure, unchanged; best measured 51.0 µs).
// =====================================================================
__global__ __launch_bounds__(256) void diff_attn(
    const f16* __restrict__ qf_, const f16* __restrict__ kf_,
    const bf16* __restrict__ vt,
    const float* __restrict__ lq1, const float* __restrict__ lk1,
    const float* __restrict__ lq2, const float* __restrict__ lk2,
    f16* __restrict__ attn)
{
  __shared__ char smem[65536];
  // buf b at b*32768: K0 @0 (8KB) | K1 @8192 (8KB) | V @16384 (16KB)
  const int tid  = threadIdx.x;
  const int wave = tid >> 6, lane = tid & 63;
  const int l32 = lane & 31, lh = lane >> 5;
  const int h  = blockIdx.x & 7;         // head pair — XCD-affine
  const int qb = blockIdx.x >> 3;        // q block 0..63 (32 rows each)
  const int hl = wave >> 1;              // head in pair
  const int ws = wave & 1;               // key-half of this wave
  const int hh = h * 2 + hl;
  const int t0 = qb * 32;

  float a1 = lq1[lane] * lk1[lane];
  float a2 = lq2[lane] * lk2[lane];
  #pragma unroll
  for (int off = 1; off < 64; off <<= 1) {
    a1 += __shfl_xor(a1, off, 64);
    a2 += __shfl_xor(a2, off, 64);
  }
  const float lam = __expf(a1) - __expf(a2) + LAMBDA_INIT;

  // Q B-frags (32 rows x 64 d): n=query=l32, k = kt*16 + lh*8 + j
  f16x8 qfr[4];
  {
    const f16* qrow = qf_ + (long)(t0 + l32) * EMB + hh * 64 + lh * 8;
    #pragma unroll
    for (int kt = 0; kt < 4; kt++) qfr[kt] = *(const f16x8*)(qrow + kt * 16);
  }

  floatx16 o[4];   // nt over Dv=128, un-normalized accumulation
  #pragma unroll
  for (int nt = 0; nt < 4; nt++)
    #pragma unroll
    for (int r = 0; r < 16; r++) o[nt][r] = 0.f;
  // denominator partials: 4-way tree to cut the serial add chain
  float lr0 = 0.f, lr1 = 0.f, lr2 = 0.f, lr3 = 0.f;

  // staging: waves 0,1 -> K0,K1; waves 2,3 -> V halves
  const int srow = lane >> 3;
  const int ch   = (lane & 7) ^ srow;
  const f16*  kgp = kf_ + (long)(h * 2 + ws) * 64 + (long)srow * EMB + ch * 8;
  const bf16* vgp = vt + (long)(h * 128 + (wave - 2) * 64 + srow) * T_SEQ + ch * 8;
  const int kofs = wave * 8192;                 // waves 0,1
  const int vofs = 16384 + (wave - 2) * 8192;   // waves 2,3

  // prologue: stage tile 0 into buffer 0
  if (wave < 2) {
    #pragma unroll
    for (int j = 0; j < 8; j++)
      gl_lds16(kgp + (long)j * 8 * EMB, smem + kofs + j * 1024);
  } else {
    #pragma unroll
    for (int j = 0; j < 8; j++)
      gl_lds16(vgp + (long)j * 8 * T_SEQ, smem + vofs + j * 1024);
  }

  for (int kb = 0; kb < T_SEQ; kb += 64) {
    const int cur = (kb >> 6) & 1;
    const char* sb = smem + cur * 32768;

    // own tile-i loads were issued a full iteration ago -> no stall
    asm volatile("s_waitcnt vmcnt(0)" ::: "memory");
    // all waves' tile-i loads landed; all waves left iter i-1
    asm volatile("s_barrier" ::: "memory");

    const f16*  Ks  = (const f16*)(sb + hl * 8192);
    const bf16* Vsb = (const bf16*)(sb + 16384);

    // ---- register staging: ALL ds_reads before any gl_lds issue ----
    f16x8 kfr[4];
    #pragma unroll
    for (int kt = 0; kt < 4; kt++) {
      int krow = ws * 32 + l32;
      int c = kt * 2 + lh;
      kfr[kt] = *(const f16x8*)(Ks + krow * 64 + ((c ^ (krow & 7)) << 3));
    }
    bf16x8 vfr[4][2];
    #pragma unroll
    for (int nt = 0; nt < 4; nt++) {
      #pragma unroll
      for (int kt = 0; kt < 2; kt++) {
        int vrow = nt * 32 + l32;
        int c = ws * 4 + kt * 2 + lh;
        vfr[nt][kt] = *(const bf16x8*)(Vsb + vrow * 64 + ((c ^ (vrow & 7)) << 3));
      }
    }

    // ---- prefetch issue (after all ds_reads in program order) ----
    if (kb + 64 < T_SEQ) {
      char* nb = smem + (cur ^ 1) * 32768;
      if (wave < 2) {
        #pragma unroll
        for (int j = 0; j < 8; j++)
          gl_lds16(kgp + (long)(kb + 64) * EMB + (long)j * 8 * EMB,
                   nb + kofs + j * 1024);
      } else {
        #pragma unroll
        for (int j = 0; j < 8; j++)
          gl_lds16(vgp + (kb + 64) + (long)j * 8 * T_SEQ,
                   nb + vofs + j * 1024);
      }
    }

    // ---- compute: pure registers from here ----
    // QK^T swapped: A=K (m=key=l32 of own half), B=Q (n=query=l32)
    floatx16 s;
    #pragma unroll
    for (int r = 0; r < 16; r++) s[r] = 0.f;
    #pragma unroll
    for (int kt = 0; kt < 4; kt++)
      s = mfma32_h(kfr[kt], qfr[kt], s);
    // static-offset softmax; denominator partials in a 4-way tree
    #pragma unroll
    for (int r = 0; r < 4; r++) {
      float p0 = __builtin_amdgcn_exp2f(
          fmaf(s[r], 1.4426950408889634f, -17.312340490667562f));
      float p1 = __builtin_amdgcn_exp2f(
          fmaf(s[r + 4], 1.4426950408889634f, -17.312340490667562f));
      float p2 = __builtin_amdgcn_exp2f(
          fmaf(s[r + 8], 1.4426950408889634f, -17.312340490667562f));
      float p3 = __builtin_amdgcn_exp2f(
          fmaf(s[r + 12], 1.4426950408889634f, -17.312340490667562f));
      s[r] = p0; s[r + 4] = p1; s[r + 8] = p2; s[r + 12] = p3;
      lr0 += p0; lr1 += p1; lr2 += p2; lr3 += p3;
    }
    // in-register P -> bf16 A-frags (cvt_pk + permlane32_swap)
    bf16x8 pf[2];
    #pragma unroll
    for (int kt = 0; kt < 2; kt++) {
      const int b0 = kt * 8;
      int w0 = cvtpk_bf16(s[b0 + 0], s[b0 + 1]);
      int w1 = cvtpk_bf16(s[b0 + 2], s[b0 + 3]);
      int w2 = cvtpk_bf16(s[b0 + 4], s[b0 + 5]);
      int w3 = cvtpk_bf16(s[b0 + 6], s[b0 + 7]);
      permswap(w0, w2);
      permswap(w1, w3);
      union { int i[4]; bf16x8 v; } u;
      u.i[0] = w0; u.i[1] = w1; u.i[2] = w2; u.i[3] = w3;
      pf[kt] = u.v;
    }
    // PV: O += P V over own keys (register V frags)
    #pragma unroll
    for (int nt = 0; nt < 4; nt++) {
      #pragma unroll
      for (int kt = 0; kt < 2; kt++)
        o[nt] = mfma32_bf(pf[kt], vfr[nt][kt], o[nt]);
    }
  }
  __syncthreads();   // loop exit sync before epilogue overwrites smem

  float lr = (lr0 + lr1) + (lr2 + lr3);
  // merge lh halves: lrw = this wave's full 32-key denominator for query l32
  float lrw = lr + __shfl_xor(lr, 32, 64);

  float* Cb = (float*)smem;                  // 2 heads x 32x128 fp32 = 32KB
  float* Lb = (float*)(smem + 32768);        // 128 denominator partials

  // phase 1: key-half ws==1 publishes raw O; all waves publish lrw
  if (ws == 1) {
    #pragma unroll
    for (int r = 0; r < 16; r++) {
      int m = (r & 3) + 8 * (r >> 2) + 4 * lh;
      #pragma unroll
      for (int nt = 0; nt < 4; nt++)
        Cb[hl * 4096 + m * 128 + nt * 32 + l32] = o[nt][r];
    }
  }
  if (lh == 0) Lb[ws * 64 + hl * 32 + l32] = lrw;
  __syncthreads();
  // phase 2: ws==0 merges halves and normalizes
  if (ws == 0) {
    #pragma unroll
    for (int r = 0; r < 16; r++) {
      int m = (r & 3) + 8 * (r >> 2) + 4 * lh;
      float inv = 1.0f / (Lb[hl * 32 + m] + Lb[64 + hl * 32 + m]);
      #pragma unroll
      for (int nt = 0; nt < 4; nt++)
        o[nt][r] = (o[nt][r] + Cb[hl * 4096 + m * 128 + nt * 32 + l32]) * inv;
    }
  }
  __syncthreads();
  // phase 3: head1 publishes normalized O1
  if (hl == 1 && ws == 0) {
    #pragma unroll
    for (int r = 0; r < 16; r++) {
      int m = (r & 3) + 8 * (r >> 2) + 4 * lh;
      #pragma unroll
      for (int nt = 0; nt < 4; nt++)
        Cb[4096 + m * 128 + nt * 32 + l32] = o[nt][r];
    }
  }
  __syncthreads();
  // phase 4: head0 does diff + rms-norm + store
  if (hl == 0 && ws == 0) {
    float ss[16];
    #pragma unroll
    for (int r = 0; r < 16; r++) {
      int m = (r & 3) + 8 * (r >> 2) + 4 * lh;
      ss[r] = 0.f;
      #pragma unroll
      for (int nt = 0; nt < 4; nt++) {
        float v = o[nt][r] - lam * Cb[4096 + m * 128 + nt * 32 + l32];
        o[nt][r] = v;
        ss[r] += v * v;
      }
    }
    #pragma unroll
    for (int r = 0; r < 16; r++) {
      ss[r] += __shfl_xor(ss[r], 1, 64);
      ss[r] += __shfl_xor(ss[r], 2, 64);
      ss[r] += __shfl_xor(ss[r], 4, 64);
      ss[r] += __shfl_xor(ss[r], 8, 64);
      ss[r] += __shfl_xor(ss[r], 16, 64);
      float rms = rsqrtf(ss[r] * (1.0f / 128.0f) + 1e-5f) * (1.0f - LAMBDA_INIT);
      int m = (r & 3) + 8 * (r >> 2) + 4 * lh;
      #pragma unroll
      for (int nt = 0; nt < 4; nt++)
        attn[(long)(t0 + m) * EMB + h * 128 + nt * 32 + l32] = (f16)(o[nt][r] * rms);
    }
  }
}

// =====================================================================
extern "C" void kernel_launch(void* const* d_in, const int* in_sizes, int n_in,
                              void* d_out, int out_size, void* d_ws, size_t ws_size,
                              hipStream_t stream)
{
  (void)in_sizes; (void)n_in; (void)out_size; (void)ws_size;
  const float* x   = (const float*)d_in[0];
  const float* Wq  = (const float*)d_in[1];
  const float* Wk  = (const float*)d_in[2];
  const float* Wv  = (const float*)d_in[3];
  const float* Wo  = (const float*)d_in[4];
  const float* lq1 = (const float*)d_in[5];
  const float* lk1 = (const float*)d_in[6];
  const float* lq2 = (const float*)d_in[7];
  const float* lk2 = (const float*)d_in[8];
  float* out = (float*)d_out;

  const size_t TM = (size_t)T_SEQ * EMB;  // 2M elems
  const size_t WM = (size_t)EMB * EMB;    // 1M elems
  bf16* vtws = (bf16*)d_ws;          // 4MB      @ 0
  f16*  aws  = (f16*)(vtws + TM);    // 4MB      @ 4MB
  f16*  xf   = aws  + TM;            // 4MB      @ 8MB
  f16*  wqf  = xf   + TM;            // 2MB      @ 12MB
  f16*  wkf  = wqf  + WM;            //          @ 14MB
  f16*  wvf  = wkf  + WM;            //          @ 16MB
  f16*  wof  = wvf  + WM;            //          @ 18MB
  f16*  qf   = wof  + WM;            // 4MB      @ 20MB
  f16*  kf   = qf   + TM;            // 4MB      @ 24MB

  // K-split partials REUSE dead regions (zero extra workspace):
  //  p0 (8MB fp32) over xf+wqf+wkf  — dead after qkv_gemm
  //  p1 (8MB fp32) over qf+kf       — dead after diff_attn
  float* p0 = (float*)xf;
  float* p1 = (float*)qf;

  convert_kernel<<<6144, 256, 0, stream>>>(x, Wq, Wk, Wv, Wo,
                                           xf, wqf, wkf, wvf, wof);
  qkv_gemm<<<768, 256, 0, stream>>>(xf, wqf, wkf, wvf, qf, kf, vtws);
  diff_attn<<<512, 256, 0, stream>>>(qf, kf, vtws, lq1, lk1, lq2, lk2, aws);
  out_gemm<<<512, 256, 0, stream>>>(aws, wof, p0, p1);
  add_out<<<2048, 256, 0, stream>>>(p0, p1, out);
}

// Round 11
// 179.400 us; speedup vs baseline: 1.1449x; 1.0671x over previous
//
#include <hip/hip_runtime.h>
#include <hip/hip_bf16.h>

typedef __hip_bfloat16 bf16;
typedef _Float16 f16;
typedef __attribute__((ext_vector_type(8))) __bf16 bf16x8;
typedef __attribute__((ext_vector_type(8))) _Float16 f16x8;
typedef __attribute__((ext_vector_type(4))) _Float16 f16x4;
typedef __attribute__((ext_vector_type(4))) float floatx4;
typedef __attribute__((ext_vector_type(16))) float floatx16;

#define T_SEQ 2048
#define EMB   1024
#define LAMBDA_INIT 0.35550906759096926f

// round-to-nearest-even fp32 -> bf16
__device__ __forceinline__ bf16 f2bf(float f) {
  unsigned u;
  __builtin_memcpy(&u, &f, 4);
  u += 0x7FFF + ((u >> 16) & 1);
  unsigned short h = (unsigned short)(u >> 16);
  bf16 r;
  __builtin_memcpy(&r, &h, 2);
  return r;
}

// v_cvt_pk_bf16_f32: d[15:0]=bf16(lo), d[31:16]=bf16(hi)
__device__ __forceinline__ int cvtpk_bf16(float lo, float hi) {
  int r;
  asm("v_cvt_pk_bf16_f32 %0, %1, %2" : "=v"(r) : "v"(lo), "v"(hi));
  return r;
}

// v_permlane32_swap_b32: swaps a's upper-32-lane half with b's lower half.
__device__ __forceinline__ void permswap(int& a, int& b) {
  asm volatile("v_permlane32_swap_b32 %0, %1" : "+v"(a), "+v"(b));
}

__device__ __forceinline__ void gl_lds16(const void* g, void* l) {
  __builtin_amdgcn_global_load_lds((const __attribute__((address_space(1))) void*)g,
                                   (__attribute__((address_space(3))) void*)l, 16, 0, 0);
}

__device__ __forceinline__ floatx4 mfma_h(f16x8 a, f16x8 b, floatx4 c) {
  return __builtin_amdgcn_mfma_f32_16x16x32_f16(a, b, c, 0, 0, 0);
}
__device__ __forceinline__ floatx16 mfma32_h(f16x8 a, f16x8 b, floatx16 c) {
  return __builtin_amdgcn_mfma_f32_32x32x16_f16(a, b, c, 0, 0, 0);
}
__device__ __forceinline__ floatx16 mfma32_bf(bf16x8 a, bf16x8 b, floatx16 c) {
  return __builtin_amdgcn_mfma_f32_32x32x16_bf16(a, b, c, 0, 0, 0);
}

// =====================================================================
// fp32 -> fp16 conversion for x, Wq, Wk, Wv, Wo.
// =====================================================================
__global__ __launch_bounds__(256) void convert_kernel(
    const float* __restrict__ x,  const float* __restrict__ wq,
    const float* __restrict__ wk, const float* __restrict__ wv,
    const float* __restrict__ wo,
    f16* __restrict__ xf, f16* __restrict__ wqf, f16* __restrict__ wkf,
    f16* __restrict__ wvf, f16* __restrict__ wof)
{
  int b = blockIdx.x;
  const float* src; f16* dst; long off;
  if      (b < 2048) { src = x;  dst = xf;  off = (long)b * 1024; }
  else if (b < 3072) { src = wq; dst = wqf; off = (long)(b - 2048) * 1024; }
  else if (b < 4096) { src = wk; dst = wkf; off = (long)(b - 3072) * 1024; }
  else if (b < 5120) { src = wv; dst = wvf; off = (long)(b - 4096) * 1024; }
  else               { src = wo; dst = wof; off = (long)(b - 5120) * 1024; }
  long i = off + threadIdx.x * 4;
  float4 v = *(const float4*)(src + i);
  f16x4 o;
  o.x = (f16)v.x; o.y = (f16)v.y; o.z = (f16)v.z; o.w = (f16)v.w;
  *(f16x4*)(dst + i) = o;
}

// =====================================================================
// fp16 NT GEMM, 64x128 tile, BK=64, 24KB LDS (r7-verified: the 24KB
// footprint -> ~6 blocks/CU is the latency-hiding resource; r8/r10's
// deeper schedules traded it away and lost. Lesson: for latency-bound
// GEMMs, block-level TLP > per-block pipeline depth.)
// Kld = row stride of A/B; Klen = K-extent (K-split support).
// MODE 2 = RoPE-Q epilogue (fold 0.125) -> fp16; MODE 3 = RoPE-K (inv)
// MODE 0 = bf16 out (V);  MODE 1 = fp32 out (output-projection partial)
// =====================================================================
template <int MODE>
__device__ __forceinline__ void gemm64x128_f16(
    const f16* __restrict__ A_, const f16* __restrict__ B_,
    void* C0v, int Kld, int Klen, int ldc, int m0, int n0, char* smem)
{
  f16* As = (f16*)smem;              // 64 x 64 swz (8 KB)
  f16* Bs = (f16*)(smem + 8192);     // 128 x 64 swz (16 KB)
  const int tid  = threadIdx.x;
  const int wave = tid >> 6, lane = tid & 63, quad = lane >> 4, l16 = lane & 15;
  const int mo = (wave & 1) << 5;
  const int no = (wave >> 1) << 6;

  floatx4 acc[2][4];
  #pragma unroll
  for (int i = 0; i < 2; i++)
    #pragma unroll
    for (int j = 0; j < 4; j++) { acc[i][j][0]=0.f; acc[i][j][1]=0.f; acc[i][j][2]=0.f; acc[i][j][3]=0.f; }

  const int srow = tid >> 3;
  const int ch   = (tid & 7) ^ (srow & 7);
  const long aoff = (long)(m0 + srow) * Kld + ch * 8;
  const long boff = (long)(n0 + srow) * Kld + ch * 8;
  const int wb = wave << 10;

  for (int k0 = 0; k0 < Klen; k0 += 64) {
    #pragma unroll
    for (int rr = 0; rr < 2; rr++)
      gl_lds16(A_ + aoff + k0 + (long)rr * 32 * Kld, smem + wb + rr * 4096);
    #pragma unroll
    for (int rr = 0; rr < 4; rr++)
      gl_lds16(B_ + boff + k0 + (long)rr * 32 * Kld, smem + 8192 + wb + rr * 4096);
    __syncthreads();
    #pragma unroll
    for (int kt = 0; kt < 2; kt++) {
      f16x8 a[2], b[4];
      #pragma unroll
      for (int i = 0; i < 2; i++) {
        int m = mo + i * 16 + l16;
        a[i] = *(const f16x8*)(As + m * 64 + ((((kt << 2) | quad) ^ (m & 7)) << 3));
      }
      #pragma unroll
      for (int j = 0; j < 4; j++) {
        int n = no + j * 16 + l16;
        b[j] = *(const f16x8*)(Bs + n * 64 + ((((kt << 2) | quad) ^ (n & 7)) << 3));
      }
      #pragma unroll
      for (int i = 0; i < 2; i++)
        #pragma unroll
        for (int j = 0; j < 4; j++)
          acc[i][j] = mfma_h(a[i], b[j], acc[i][j]);
    }
    __syncthreads();
  }

  if (MODE == 1) {
    #pragma unroll
    for (int i = 0; i < 2; i++)
      #pragma unroll
      for (int j = 0; j < 4; j++)
        #pragma unroll
        for (int r = 0; r < 4; r++) {
          int row = m0 + mo + i * 16 + quad * 4 + r;
          int col = n0 + no + j * 16 + l16;
          ((float*)C0v)[(long)row * ldc + col] = acc[i][j][r];
        }
  } else {
    unsigned short* E = (unsigned short*)smem;   // 64x128 2-byte = 16 KB
    #pragma unroll
    for (int i = 0; i < 2; i++)
      #pragma unroll
      for (int j = 0; j < 4; j++)
        #pragma unroll
        for (int r = 0; r < 4; r++) {
          int row = mo + i * 16 + quad * 4 + r;
          int col = no + j * 16 + l16;
          float v = acc[i][j][r];
          unsigned short bits;
          if (MODE == 0) {
            bf16 t = f2bf(v);
            __builtin_memcpy(&bits, &t, 2);
          } else {
            float p = __shfl_xor(v, 1, 64);
            int d = col & 63;
            float fr = (float)(m0 + row) * __expf((float)(d >> 1) * -0.28782313662425574f);
            float sn, cs;
            sincosf(fr, &sn, &cs);
            float rot = (col & 1) ? fmaf(v, cs, p * sn) : fmaf(v, cs, -p * sn);
            float power = (float)(m0 + row - 1024) * (1.0f / 512.0f);
            if (MODE == 3) power = -power;
            float sv = fmaf(2.0f, (float)(d & 31), 25.6f) * (1.0f / 89.6f);
            float s = __expf(power * __logf(sv));
            float ov = rot * s;
            if (MODE == 2) ov *= 0.125f;
            f16 t = (f16)ov;
            __builtin_memcpy(&bits, &t, 2);
          }
          E[row * 128 + col] = bits;
        }
    __syncthreads();
    const int rr0 = tid >> 4;
    const int c8  = (tid & 15) * 8;
    #pragma unroll
    for (int p2 = 0; p2 < 4; p2++) {
      int row = p2 * 16 + rr0;
      *(uint4*)((unsigned short*)C0v + (long)(m0 + row) * ldc + n0 + c8) =
          *(const uint4*)(E + row * 128 + c8);
    }
  }
}

// =====================================================================
// qkv_gemm with bijective XCD-chunked swizzle (T1). HW assigns XCD =
// hw_bid % 8; remapping wgid = (bid%8)*96 + bid/8 gives each XCD one
// CONTIGUOUS 96-block work chunk. Per-XCD L2 footprint drops from
// "all of xf, 3x" (~12MB, thrash) to a 1.5MB xf row-slice + one 2MB
// weight (~3.5MB <= 4MB L2). Round-10 FETCH=27MB (3x inputs) is the
// duplication this removes.
// =====================================================================
__global__ __launch_bounds__(256) void qkv_gemm(
    const f16* __restrict__ xf,
    const f16* __restrict__ wqf, const f16* __restrict__ wkf,
    const f16* __restrict__ wvf,
    f16* __restrict__ qf, f16* __restrict__ kf, bf16* __restrict__ vt)
{
  __shared__ char smem[24576];
  const int bid = blockIdx.x;
  int wgid = (bid & 7) * 96 + (bid >> 3);   // nwg=768 ≡ 0 (mod 8): bijective
  if (wgid < 256) {
    gemm64x128_f16<2>(xf, wqf, qf, 1024, 1024, 1024, (wgid >> 3) * 64, (wgid & 7) * 128, smem);
  } else if (wgid < 512) {
    wgid -= 256;
    gemm64x128_f16<3>(xf, wkf, kf, 1024, 1024, 1024, (wgid >> 3) * 64, (wgid & 7) * 128, smem);
  } else {
    wgid -= 512;
    gemm64x128_f16<0>(wvf, xf, vt, 1024, 1024, 2048, (wgid >> 4) * 64, (wgid & 15) * 128, smem);
  }
}

// out_gemm K-split by 2 (512 blocks, 2/CU) + XCD-chunked swizzle:
// each XCD gets 64 contiguous blocks -> ~0.5MB attn slice + ~1MB wof
// half -> L2-resident.
__global__ __launch_bounds__(256) void out_gemm(const f16* __restrict__ attn,
                                                const f16* __restrict__ Wo,
                                                float* __restrict__ p0,
                                                float* __restrict__ p1)
{
  __shared__ char smem[24576];
  const int bid = blockIdx.x;
  const int wgid = (bid & 7) * 64 + (bid >> 3);   // nwg=512: bijective
  const int kh = wgid >> 8;      // K-half 0/1
  const int b  = wgid & 255;
  float* pb = kh ? p1 : p0;
  gemm64x128_f16<1>(attn + kh * 512, Wo + kh * 512, pb, 1024, 512, 1024,
                    (b >> 3) * 64, (b & 7) * 128, smem);
}

__global__ __launch_bounds__(256) void add_out(const float* __restrict__ p0,
                                               const float* __restrict__ p1,
                                               float* __restrict__ out)
{
  long i = ((long)blockIdx.x * 256 + threadIdx.x) * 4;
  float4 a = *(const float4*)(p0 + i);
  float4 b = *(const float4*)(p1 + i);
  float4 c;
  c.x = a.x + b.x; c.y = a.y + b.y; c.z = a.z + b.z; c.w = a.w + b.w;
  *(float4*)(out + i) = c;
}

// =====================================================================
// Differential flash attention — register-staged single-barrier edition
// (round-5 structure, unchanged; best measured 51.0 µs).
// =====================================================================
__global__ __launch_bounds__(256) void diff_attn(
    const f16* __restrict__ qf_, const f16* __restrict__ kf_,
    const bf16* __restrict__ vt,
    const float* __restrict__ lq1, const float* __restrict__ lk1,
    const float* __restrict__ lq2, const float* __restrict__ lk2,
    f16* __restrict__ attn)
{
  __shared__ char smem[65536];
  // buf b at b*32768: K0 @0 (8KB) | K1 @8192 (8KB) | V @16384 (16KB)
  const int tid  = threadIdx.x;
  const int wave = tid >> 6, lane = tid & 63;
  const int l32 = lane & 31, lh = lane >> 5;
  const int h  = blockIdx.x & 7;         // head pair — XCD-affine
  const int qb = blockIdx.x >> 3;        // q block 0..63 (32 rows each)
  const int hl = wave >> 1;              // head in pair
  const int ws = wave & 1;               // key-half of this wave
  const int hh = h * 2 + hl;
  const int t0 = qb * 32;

  float a1 = lq1[lane] * lk1[lane];
  float a2 = lq2[lane] * lk2[lane];
  #pragma unroll
  for (int off = 1; off < 64; off <<= 1) {
    a1 += __shfl_xor(a1, off, 64);
    a2 += __shfl_xor(a2, off, 64);
  }
  const float lam = __expf(a1) - __expf(a2) + LAMBDA_INIT;

  // Q B-frags (32 rows x 64 d): n=query=l32, k = kt*16 + lh*8 + j
  f16x8 qfr[4];
  {
    const f16* qrow = qf_ + (long)(t0 + l32) * EMB + hh * 64 + lh * 8;
    #pragma unroll
    for (int kt = 0; kt < 4; kt++) qfr[kt] = *(const f16x8*)(qrow + kt * 16);
  }

  floatx16 o[4];   // nt over Dv=128, un-normalized accumulation
  #pragma unroll
  for (int nt = 0; nt < 4; nt++)
    #pragma unroll
    for (int r = 0; r < 16; r++) o[nt][r] = 0.f;
  // denominator partials: 4-way tree to cut the serial add chain
  float lr0 = 0.f, lr1 = 0.f, lr2 = 0.f, lr3 = 0.f;

  // staging: waves 0,1 -> K0,K1; waves 2,3 -> V halves
  const int srow = lane >> 3;
  const int ch   = (lane & 7) ^ srow;
  const f16*  kgp = kf_ + (long)(h * 2 + ws) * 64 + (long)srow * EMB + ch * 8;
  const bf16* vgp = vt + (long)(h * 128 + (wave - 2) * 64 + srow) * T_SEQ + ch * 8;
  const int kofs = wave * 8192;                 // waves 0,1
  const int vofs = 16384 + (wave - 2) * 8192;   // waves 2,3

  // prologue: stage tile 0 into buffer 0
  if (wave < 2) {
    #pragma unroll
    for (int j = 0; j < 8; j++)
      gl_lds16(kgp + (long)j * 8 * EMB, smem + kofs + j * 1024);
  } else {
    #pragma unroll
    for (int j = 0; j < 8; j++)
      gl_lds16(vgp + (long)j * 8 * T_SEQ, smem + vofs + j * 1024);
  }

  for (int kb = 0; kb < T_SEQ; kb += 64) {
    const int cur = (kb >> 6) & 1;
    const char* sb = smem + cur * 32768;

    // own tile-i loads were issued a full iteration ago -> no stall
    asm volatile("s_waitcnt vmcnt(0)" ::: "memory");
    // all waves' tile-i loads landed; all waves left iter i-1
    asm volatile("s_barrier" ::: "memory");

    const f16*  Ks  = (const f16*)(sb + hl * 8192);
    const bf16* Vsb = (const bf16*)(sb + 16384);

    // ---- register staging: ALL ds_reads before any gl_lds issue ----
    f16x8 kfr[4];
    #pragma unroll
    for (int kt = 0; kt < 4; kt++) {
      int krow = ws * 32 + l32;
      int c = kt * 2 + lh;
      kfr[kt] = *(const f16x8*)(Ks + krow * 64 + ((c ^ (krow & 7)) << 3));
    }
    bf16x8 vfr[4][2];
    #pragma unroll
    for (int nt = 0; nt < 4; nt++) {
      #pragma unroll
      for (int kt = 0; kt < 2; kt++) {
        int vrow = nt * 32 + l32;
        int c = ws * 4 + kt * 2 + lh;
        vfr[nt][kt] = *(const bf16x8*)(Vsb + vrow * 64 + ((c ^ (vrow & 7)) << 3));
      }
    }

    // ---- prefetch issue (after all ds_reads in program order) ----
    if (kb + 64 < T_SEQ) {
      char* nb = smem + (cur ^ 1) * 32768;
      if (wave < 2) {
        #pragma unroll
        for (int j = 0; j < 8; j++)
          gl_lds16(kgp + (long)(kb + 64) * EMB + (long)j * 8 * EMB,
                   nb + kofs + j * 1024);
      } else {
        #pragma unroll
        for (int j = 0; j < 8; j++)
          gl_lds16(vgp + (kb + 64) + (long)j * 8 * T_SEQ,
                   nb + vofs + j * 1024);
      }
    }

    // ---- compute: pure registers from here ----
    // QK^T swapped: A=K (m=key=l32 of own half), B=Q (n=query=l32)
    floatx16 s;
    #pragma unroll
    for (int r = 0; r < 16; r++) s[r] = 0.f;
    #pragma unroll
    for (int kt = 0; kt < 4; kt++)
      s = mfma32_h(kfr[kt], qfr[kt], s);
    // static-offset softmax; denominator partials in a 4-way tree
    #pragma unroll
    for (int r = 0; r < 4; r++) {
      float p0 = __builtin_amdgcn_exp2f(
          fmaf(s[r], 1.4426950408889634f, -17.312340490667562f));
      float p1 = __builtin_amdgcn_exp2f(
          fmaf(s[r + 4], 1.4426950408889634f, -17.312340490667562f));
      float p2 = __builtin_amdgcn_exp2f(
          fmaf(s[r + 8], 1.4426950408889634f, -17.312340490667562f));
      float p3 = __builtin_amdgcn_exp2f(
          fmaf(s[r + 12], 1.4426950408889634f, -17.312340490667562f));
      s[r] = p0; s[r + 4] = p1; s[r + 8] = p2; s[r + 12] = p3;
      lr0 += p0; lr1 += p1; lr2 += p2; lr3 += p3;
    }
    // in-register P -> bf16 A-frags (cvt_pk + permlane32_swap)
    bf16x8 pf[2];
    #pragma unroll
    for (int kt = 0; kt < 2; kt++) {
      const int b0 = kt * 8;
      int w0 = cvtpk_bf16(s[b0 + 0], s[b0 + 1]);
      int w1 = cvtpk_bf16(s[b0 + 2], s[b0 + 3]);
      int w2 = cvtpk_bf16(s[b0 + 4], s[b0 + 5]);
      int w3 = cvtpk_bf16(s[b0 + 6], s[b0 + 7]);
      permswap(w0, w2);
      permswap(w1, w3);
      union { int i[4]; bf16x8 v; } u;
      u.i[0] = w0; u.i[1] = w1; u.i[2] = w2; u.i[3] = w3;
      pf[kt] = u.v;
    }
    // PV: O += P V over own keys (register V frags)
    #pragma unroll
    for (int nt = 0; nt < 4; nt++) {
      #pragma unroll
      for (int kt = 0; kt < 2; kt++)
        o[nt] = mfma32_bf(pf[kt], vfr[nt][kt], o[nt]);
    }
  }
  __syncthreads();   // loop exit sync before epilogue overwrites smem

  float lr = (lr0 + lr1) + (lr2 + lr3);
  // merge lh halves: lrw = this wave's full 32-key denominator for query l32
  float lrw = lr + __shfl_xor(lr, 32, 64);

  float* Cb = (float*)smem;                  // 2 heads x 32x128 fp32 = 32KB
  float* Lb = (float*)(smem + 32768);        // 128 denominator partials

  // phase 1: key-half ws==1 publishes raw O; all waves publish lrw
  if (ws == 1) {
    #pragma unroll
    for (int r = 0; r < 16; r++) {
      int m = (r & 3) + 8 * (r >> 2) + 4 * lh;
      #pragma unroll
      for (int nt = 0; nt < 4; nt++)
        Cb[hl * 4096 + m * 128 + nt * 32 + l32] = o[nt][r];
    }
  }
  if (lh == 0) Lb[ws * 64 + hl * 32 + l32] = lrw;
  __syncthreads();
  // phase 2: ws==0 merges halves and normalizes
  if (ws == 0) {
    #pragma unroll
    for (int r = 0; r < 16; r++) {
      int m = (r & 3) + 8 * (r >> 2) + 4 * lh;
      float inv = 1.0f / (Lb[hl * 32 + m] + Lb[64 + hl * 32 + m]);
      #pragma unroll
      for (int nt = 0; nt < 4; nt++)
        o[nt][r] = (o[nt][r] + Cb[hl * 4096 + m * 128 + nt * 32 + l32]) * inv;
    }
  }
  __syncthreads();
  // phase 3: head1 publishes normalized O1
  if (hl == 1 && ws == 0) {
    #pragma unroll
    for (int r = 0; r < 16; r++) {
      int m = (r & 3) + 8 * (r >> 2) + 4 * lh;
      #pragma unroll
      for (int nt = 0; nt < 4; nt++)
        Cb[4096 + m * 128 + nt * 32 + l32] = o[nt][r];
    }
  }
  __syncthreads();
  // phase 4: head0 does diff + rms-norm + store
  if (hl == 0 && ws == 0) {
    float ss[16];
    #pragma unroll
    for (int r = 0; r < 16; r++) {
      int m = (r & 3) + 8 * (r >> 2) + 4 * lh;
      ss[r] = 0.f;
      #pragma unroll
      for (int nt = 0; nt < 4; nt++) {
        float v = o[nt][r] - lam * Cb[4096 + m * 128 + nt * 32 + l32];
        o[nt][r] = v;
        ss[r] += v * v;
      }
    }
    #pragma unroll
    for (int r = 0; r < 16; r++) {
      ss[r] += __shfl_xor(ss[r], 1, 64);
      ss[r] += __shfl_xor(ss[r], 2, 64);
      ss[r] += __shfl_xor(ss[r], 4, 64);
      ss[r] += __shfl_xor(ss[r], 8, 64);
      ss[r] += __shfl_xor(ss[r], 16, 64);
      float rms = rsqrtf(ss[r] * (1.0f / 128.0f) + 1e-5f) * (1.0f - LAMBDA_INIT);
      int m = (r & 3) + 8 * (r >> 2) + 4 * lh;
      #pragma unroll
      for (int nt = 0; nt < 4; nt++)
        attn[(long)(t0 + m) * EMB + h * 128 + nt * 32 + l32] = (f16)(o[nt][r] * rms);
    }
  }
}

// =====================================================================
extern "C" void kernel_launch(void* const* d_in, const int* in_sizes, int n_in,
                              void* d_out, int out_size, void* d_ws, size_t ws_size,
                              hipStream_t stream)
{
  (void)in_sizes; (void)n_in; (void)out_size; (void)ws_size;
  const float* x   = (const float*)d_in[0];
  const float* Wq  = (const float*)d_in[1];
  const float* Wk  = (const float*)d_in[2];
  const float* Wv  = (const float*)d_in[3];
  const float* Wo  = (const float*)d_in[4];
  const float* lq1 = (const float*)d_in[5];
  const float* lk1 = (const float*)d_in[6];
  const float* lq2 = (const float*)d_in[7];
  const float* lk2 = (const float*)d_in[8];
  float* out = (float*)d_out;

  const size_t TM = (size_t)T_SEQ * EMB;  // 2M elems
  const size_t WM = (size_t)EMB * EMB;    // 1M elems
  bf16* vtws = (bf16*)d_ws;          // 4MB      @ 0
  f16*  aws  = (f16*)(vtws + TM);    // 4MB      @ 4MB
  f16*  xf   = aws  + TM;            // 4MB      @ 8MB
  f16*  wqf  = xf   + TM;            // 2MB      @ 12MB
  f16*  wkf  = wqf  + WM;            //          @ 14MB
  f16*  wvf  = wkf  + WM;            //          @ 16MB
  f16*  wof  = wvf  + WM;            //          @ 18MB
  f16*  qf   = wof  + WM;            // 4MB      @ 20MB
  f16*  kf   = qf   + TM;            // 4MB      @ 24MB

  // K-split partials REUSE dead regions (zero extra workspace):
  //  p0 (8MB fp32) over xf+wqf+wkf  — dead after qkv_gemm
  //  p1 (8MB fp32) over qf+kf       — dead after diff_attn
  float* p0 = (float*)xf;
  float* p1 = (float*)qf;

  convert_kernel<<<6144, 256, 0, stream>>>(x, Wq, Wk, Wv, Wo,
                                           xf, wqf, wkf, wvf, wof);
  qkv_gemm<<<768, 256, 0, stream>>>(xf, wqf, wkf, wvf, qf, kf, vtws);
  diff_attn<<<512, 256, 0, stream>>>(qf, kf, vtws, lq1, lk1, lq2, lk2, aws);
  out_gemm<<<512, 256, 0, stream>>>(aws, wof, p0, p1);
  add_out<<<2048, 256, 0, stream>>>(p0, p1, out);
}

// Round 12
// 173.236 us; speedup vs baseline: 1.1856x; 1.0356x over previous
//
#include <hip/hip_runtime.h>
#include <hip/hip_bf16.h>

typedef __hip_bfloat16 bf16;
typedef _Float16 f16;
typedef __attribute__((ext_vector_type(8))) __bf16 bf16x8;
typedef __attribute__((ext_vector_type(8))) _Float16 f16x8;
typedef __attribute__((ext_vector_type(4))) _Float16 f16x4;
typedef __attribute__((ext_vector_type(4))) float floatx4;
typedef __attribute__((ext_vector_type(16))) float floatx16;

#define T_SEQ 2048
#define EMB   1024
#define LAMBDA_INIT 0.35550906759096926f

// round-to-nearest-even fp32 -> bf16
__device__ __forceinline__ bf16 f2bf(float f) {
  unsigned u;
  __builtin_memcpy(&u, &f, 4);
  u += 0x7FFF + ((u >> 16) & 1);
  unsigned short h = (unsigned short)(u >> 16);
  bf16 r;
  __builtin_memcpy(&r, &h, 2);
  return r;
}

// v_cvt_pk_bf16_f32: d[15:0]=bf16(lo), d[31:16]=bf16(hi)
__device__ __forceinline__ int cvtpk_bf16(float lo, float hi) {
  int r;
  asm("v_cvt_pk_bf16_f32 %0, %1, %2" : "=v"(r) : "v"(lo), "v"(hi));
  return r;
}

// v_permlane32_swap_b32: swaps a's upper-32-lane half with b's lower half.
__device__ __forceinline__ void permswap(int& a, int& b) {
  asm volatile("v_permlane32_swap_b32 %0, %1" : "+v"(a), "+v"(b));
}

__device__ __forceinline__ void gl_lds16(const void* g, void* l) {
  __builtin_amdgcn_global_load_lds((const __attribute__((address_space(1))) void*)g,
                                   (__attribute__((address_space(3))) void*)l, 16, 0, 0);
}

__device__ __forceinline__ floatx4 mfma_h(f16x8 a, f16x8 b, floatx4 c) {
  return __builtin_amdgcn_mfma_f32_16x16x32_f16(a, b, c, 0, 0, 0);
}
__device__ __forceinline__ floatx16 mfma32_h(f16x8 a, f16x8 b, floatx16 c) {
  return __builtin_amdgcn_mfma_f32_32x32x16_f16(a, b, c, 0, 0, 0);
}
__device__ __forceinline__ floatx16 mfma32_bf(bf16x8 a, bf16x8 b, floatx16 c) {
  return __builtin_amdgcn_mfma_f32_32x32x16_bf16(a, b, c, 0, 0, 0);
}

// =====================================================================
// fp32 -> fp16 conversion for x, Wq, Wk, Wv, Wo.
// =====================================================================
__global__ __launch_bounds__(256) void convert_kernel(
    const float* __restrict__ x,  const float* __restrict__ wq,
    const float* __restrict__ wk, const float* __restrict__ wv,
    const float* __restrict__ wo,
    f16* __restrict__ xf, f16* __restrict__ wqf, f16* __restrict__ wkf,
    f16* __restrict__ wvf, f16* __restrict__ wof)
{
  int b = blockIdx.x;
  const float* src; f16* dst; long off;
  if      (b < 2048) { src = x;  dst = xf;  off = (long)b * 1024; }
  else if (b < 3072) { src = wq; dst = wqf; off = (long)(b - 2048) * 1024; }
  else if (b < 4096) { src = wk; dst = wkf; off = (long)(b - 3072) * 1024; }
  else if (b < 5120) { src = wv; dst = wvf; off = (long)(b - 4096) * 1024; }
  else               { src = wo; dst = wof; off = (long)(b - 5120) * 1024; }
  long i = off + threadIdx.x * 4;
  float4 v = *(const float4*)(src + i);
  f16x4 o;
  o.x = (f16)v.x; o.y = (f16)v.y; o.z = (f16)v.z; o.w = (f16)v.w;
  *(f16x4*)(dst + i) = o;
}

// =====================================================================
// fp16 NT GEMM, 64x128 tile, BK=64, 24KB LDS (r7-verified best-total
// config: 24KB footprint keeps block-level TLP, which measurement shows
// is the latency-hiding resource — deeper per-block schedules [r8 reg-
// staged, r9 direct, r10 depth-2 vmcnt, r11 XCD swizzle] were neutral
// to negative). Kld = row stride; Klen = K-extent (K-split support).
// MODE 2 = RoPE-Q epilogue (fold 0.125) -> fp16; MODE 3 = RoPE-K (inv)
// MODE 0 = bf16 out (V);  MODE 1 = fp32 out (output-projection partial)
// =====================================================================
template <int MODE>
__device__ __forceinline__ void gemm64x128_f16(
    const f16* __restrict__ A_, const f16* __restrict__ B_,
    void* C0v, int Kld, int Klen, int ldc, int m0, int n0, char* smem)
{
  f16* As = (f16*)smem;              // 64 x 64 swz (8 KB)
  f16* Bs = (f16*)(smem + 8192);     // 128 x 64 swz (16 KB)
  const int tid  = threadIdx.x;
  const int wave = tid >> 6, lane = tid & 63, quad = lane >> 4, l16 = lane & 15;
  const int mo = (wave & 1) << 5;
  const int no = (wave >> 1) << 6;

  floatx4 acc[2][4];
  #pragma unroll
  for (int i = 0; i < 2; i++)
    #pragma unroll
    for (int j = 0; j < 4; j++) { acc[i][j][0]=0.f; acc[i][j][1]=0.f; acc[i][j][2]=0.f; acc[i][j][3]=0.f; }

  const int srow = tid >> 3;
  const int ch   = (tid & 7) ^ (srow & 7);
  const long aoff = (long)(m0 + srow) * Kld + ch * 8;
  const long boff = (long)(n0 + srow) * Kld + ch * 8;
  const int wb = wave << 10;

  for (int k0 = 0; k0 < Klen; k0 += 64) {
    #pragma unroll
    for (int rr = 0; rr < 2; rr++)
      gl_lds16(A_ + aoff + k0 + (long)rr * 32 * Kld, smem + wb + rr * 4096);
    #pragma unroll
    for (int rr = 0; rr < 4; rr++)
      gl_lds16(B_ + boff + k0 + (long)rr * 32 * Kld, smem + 8192 + wb + rr * 4096);
    __syncthreads();
    #pragma unroll
    for (int kt = 0; kt < 2; kt++) {
      f16x8 a[2], b[4];
      #pragma unroll
      for (int i = 0; i < 2; i++) {
        int m = mo + i * 16 + l16;
        a[i] = *(const f16x8*)(As + m * 64 + ((((kt << 2) | quad) ^ (m & 7)) << 3));
      }
      #pragma unroll
      for (int j = 0; j < 4; j++) {
        int n = no + j * 16 + l16;
        b[j] = *(const f16x8*)(Bs + n * 64 + ((((kt << 2) | quad) ^ (n & 7)) << 3));
      }
      #pragma unroll
      for (int i = 0; i < 2; i++)
        #pragma unroll
        for (int j = 0; j < 4; j++)
          acc[i][j] = mfma_h(a[i], b[j], acc[i][j]);
    }
    __syncthreads();
  }

  if (MODE == 1) {
    #pragma unroll
    for (int i = 0; i < 2; i++)
      #pragma unroll
      for (int j = 0; j < 4; j++)
        #pragma unroll
        for (int r = 0; r < 4; r++) {
          int row = m0 + mo + i * 16 + quad * 4 + r;
          int col = n0 + no + j * 16 + l16;
          ((float*)C0v)[(long)row * ldc + col] = acc[i][j][r];
        }
  } else {
    unsigned short* E = (unsigned short*)smem;   // 64x128 2-byte = 16 KB
    #pragma unroll
    for (int i = 0; i < 2; i++)
      #pragma unroll
      for (int j = 0; j < 4; j++)
        #pragma unroll
        for (int r = 0; r < 4; r++) {
          int row = mo + i * 16 + quad * 4 + r;
          int col = no + j * 16 + l16;
          float v = acc[i][j][r];
          unsigned short bits;
          if (MODE == 0) {
            bf16 t = f2bf(v);
            __builtin_memcpy(&bits, &t, 2);
          } else {
            float p = __shfl_xor(v, 1, 64);
            int d = col & 63;
            float fr = (float)(m0 + row) * __expf((float)(d >> 1) * -0.28782313662425574f);
            float sn, cs;
            sincosf(fr, &sn, &cs);
            float rot = (col & 1) ? fmaf(v, cs, p * sn) : fmaf(v, cs, -p * sn);
            float power = (float)(m0 + row - 1024) * (1.0f / 512.0f);
            if (MODE == 3) power = -power;
            float sv = fmaf(2.0f, (float)(d & 31), 25.6f) * (1.0f / 89.6f);
            float s = __expf(power * __logf(sv));
            float ov = rot * s;
            if (MODE == 2) ov *= 0.125f;
            f16 t = (f16)ov;
            __builtin_memcpy(&bits, &t, 2);
          }
          E[row * 128 + col] = bits;
        }
    __syncthreads();
    const int rr0 = tid >> 4;
    const int c8  = (tid & 15) * 8;
    #pragma unroll
    for (int p2 = 0; p2 < 4; p2++) {
      int row = p2 * 16 + rr0;
      *(uint4*)((unsigned short*)C0v + (long)(m0 + row) * ldc + n0 + c8) =
          *(const uint4*)(E + row * 128 + c8);
    }
  }
}

__global__ __launch_bounds__(256) void qkv_gemm(
    const f16* __restrict__ xf,
    const f16* __restrict__ wqf, const f16* __restrict__ wkf,
    const f16* __restrict__ wvf,
    f16* __restrict__ qf, f16* __restrict__ kf, bf16* __restrict__ vt)
{
  __shared__ char smem[24576];
  int bid = blockIdx.x;
  if (bid < 256) {
    gemm64x128_f16<2>(xf, wqf, qf, 1024, 1024, 1024, (bid >> 3) * 64, (bid & 7) * 128, smem);
  } else if (bid < 512) {
    bid -= 256;
    gemm64x128_f16<3>(xf, wkf, kf, 1024, 1024, 1024, (bid >> 3) * 64, (bid & 7) * 128, smem);
  } else {
    bid -= 512;
    gemm64x128_f16<0>(wvf, xf, vt, 1024, 1024, 2048, (bid >> 4) * 64, (bid & 15) * 128, smem);
  }
}

// out_gemm K-split by 2: 512 blocks (2/CU) each accumulate a 64x128 fp32
// partial over half of K; add_out merges. (Fixes the 256-block = 1/CU
// starvation; measured −4.4 µs in r7.)
__global__ __launch_bounds__(256) void out_gemm(const f16* __restrict__ attn,
                                                const f16* __restrict__ Wo,
                                                float* __restrict__ p0,
                                                float* __restrict__ p1)
{
  __shared__ char smem[24576];
  int bid = blockIdx.x;
  const int kh = bid >> 8;       // K-half 0/1
  const int b  = bid & 255;
  float* pb = kh ? p1 : p0;
  gemm64x128_f16<1>(attn + kh * 512, Wo + kh * 512, pb, 1024, 512, 1024,
                    (b >> 3) * 64, (b & 7) * 128, smem);
}

__global__ __launch_bounds__(256) void add_out(const float* __restrict__ p0,
                                               const float* __restrict__ p1,
                                               float* __restrict__ out)
{
  long i = ((long)blockIdx.x * 256 + threadIdx.x) * 4;
  float4 a = *(const float4*)(p0 + i);
  float4 b = *(const float4*)(p1 + i);
  float4 c;
  c.x = a.x + b.x; c.y = a.y + b.y; c.z = a.z + b.z; c.w = a.w + b.w;
  *(float4*)(out + i) = c;
}

// =====================================================================
// Differential flash attention — register-staged single-barrier edition
// (round-5 structure, unchanged; best measured 51.0 µs).
// =====================================================================
__global__ __launch_bounds__(256) void diff_attn(
    const f16* __restrict__ qf_, const f16* __restrict__ kf_,
    const bf16* __restrict__ vt,
    const float* __restrict__ lq1, const float* __restrict__ lk1,
    const float* __restrict__ lq2, const float* __restrict__ lk2,
    f16* __restrict__ attn)
{
  __shared__ char smem[65536];
  // buf b at b*32768: K0 @0 (8KB) | K1 @8192 (8KB) | V @16384 (16KB)
  const int tid  = threadIdx.x;
  const int wave = tid >> 6, lane = tid & 63;
  const int l32 = lane & 31, lh = lane >> 5;
  const int h  = blockIdx.x & 7;         // head pair — XCD-affine
  const int qb = blockIdx.x >> 3;        // q block 0..63 (32 rows each)
  const int hl = wave >> 1;              // head in pair
  const int ws = wave & 1;               // key-half of this wave
  const int hh = h * 2 + hl;
  const int t0 = qb * 32;

  float a1 = lq1[lane] * lk1[lane];
  float a2 = lq2[lane] * lk2[lane];
  #pragma unroll
  for (int off = 1; off < 64; off <<= 1) {
    a1 += __shfl_xor(a1, off, 64);
    a2 += __shfl_xor(a2, off, 64);
  }
  const float lam = __expf(a1) - __expf(a2) + LAMBDA_INIT;

  // Q B-frags (32 rows x 64 d): n=query=l32, k = kt*16 + lh*8 + j
  f16x8 qfr[4];
  {
    const f16* qrow = qf_ + (long)(t0 + l32) * EMB + hh * 64 + lh * 8;
    #pragma unroll
    for (int kt = 0; kt < 4; kt++) qfr[kt] = *(const f16x8*)(qrow + kt * 16);
  }

  floatx16 o[4];   // nt over Dv=128, un-normalized accumulation
  #pragma unroll
  for (int nt = 0; nt < 4; nt++)
    #pragma unroll
    for (int r = 0; r < 16; r++) o[nt][r] = 0.f;
  // denominator partials: 4-way tree to cut the serial add chain
  float lr0 = 0.f, lr1 = 0.f, lr2 = 0.f, lr3 = 0.f;

  // staging: waves 0,1 -> K0,K1; waves 2,3 -> V halves
  const int srow = lane >> 3;
  const int ch   = (lane & 7) ^ srow;
  const f16*  kgp = kf_ + (long)(h * 2 + ws) * 64 + (long)srow * EMB + ch * 8;
  const bf16* vgp = vt + (long)(h * 128 + (wave - 2) * 64 + srow) * T_SEQ + ch * 8;
  const int kofs = wave * 8192;                 // waves 0,1
  const int vofs = 16384 + (wave - 2) * 8192;   // waves 2,3

  // prologue: stage tile 0 into buffer 0
  if (wave < 2) {
    #pragma unroll
    for (int j = 0; j < 8; j++)
      gl_lds16(kgp + (long)j * 8 * EMB, smem + kofs + j * 1024);
  } else {
    #pragma unroll
    for (int j = 0; j < 8; j++)
      gl_lds16(vgp + (long)j * 8 * T_SEQ, smem + vofs + j * 1024);
  }

  for (int kb = 0; kb < T_SEQ; kb += 64) {
    const int cur = (kb >> 6) & 1;
    const char* sb = smem + cur * 32768;

    // own tile-i loads were issued a full iteration ago -> no stall
    asm volatile("s_waitcnt vmcnt(0)" ::: "memory");
    // all waves' tile-i loads landed; all waves left iter i-1
    asm volatile("s_barrier" ::: "memory");

    const f16*  Ks  = (const f16*)(sb + hl * 8192);
    const bf16* Vsb = (const bf16*)(sb + 16384);

    // ---- register staging: ALL ds_reads before any gl_lds issue ----
    f16x8 kfr[4];
    #pragma unroll
    for (int kt = 0; kt < 4; kt++) {
      int krow = ws * 32 + l32;
      int c = kt * 2 + lh;
      kfr[kt] = *(const f16x8*)(Ks + krow * 64 + ((c ^ (krow & 7)) << 3));
    }
    bf16x8 vfr[4][2];
    #pragma unroll
    for (int nt = 0; nt < 4; nt++) {
      #pragma unroll
      for (int kt = 0; kt < 2; kt++) {
        int vrow = nt * 32 + l32;
        int c = ws * 4 + kt * 2 + lh;
        vfr[nt][kt] = *(const bf16x8*)(Vsb + vrow * 64 + ((c ^ (vrow & 7)) << 3));
      }
    }

    // ---- prefetch issue (after all ds_reads in program order) ----
    if (kb + 64 < T_SEQ) {
      char* nb = smem + (cur ^ 1) * 32768;
      if (wave < 2) {
        #pragma unroll
        for (int j = 0; j < 8; j++)
          gl_lds16(kgp + (long)(kb + 64) * EMB + (long)j * 8 * EMB,
                   nb + kofs + j * 1024);
      } else {
        #pragma unroll
        for (int j = 0; j < 8; j++)
          gl_lds16(vgp + (kb + 64) + (long)j * 8 * T_SEQ,
                   nb + vofs + j * 1024);
      }
    }

    // ---- compute: pure registers from here ----
    // QK^T swapped: A=K (m=key=l32 of own half), B=Q (n=query=l32)
    floatx16 s;
    #pragma unroll
    for (int r = 0; r < 16; r++) s[r] = 0.f;
    #pragma unroll
    for (int kt = 0; kt < 4; kt++)
      s = mfma32_h(kfr[kt], qfr[kt], s);
    // static-offset softmax; denominator partials in a 4-way tree
    #pragma unroll
    for (int r = 0; r < 4; r++) {
      float p0 = __builtin_amdgcn_exp2f(
          fmaf(s[r], 1.4426950408889634f, -17.312340490667562f));
      float p1 = __builtin_amdgcn_exp2f(
          fmaf(s[r + 4], 1.4426950408889634f, -17.312340490667562f));
      float p2 = __builtin_amdgcn_exp2f(
          fmaf(s[r + 8], 1.4426950408889634f, -17.312340490667562f));
      float p3 = __builtin_amdgcn_exp2f(
          fmaf(s[r + 12], 1.4426950408889634f, -17.312340490667562f));
      s[r] = p0; s[r + 4] = p1; s[r + 8] = p2; s[r + 12] = p3;
      lr0 += p0; lr1 += p1; lr2 += p2; lr3 += p3;
    }
    // in-register P -> bf16 A-frags (cvt_pk + permlane32_swap)
    bf16x8 pf[2];
    #pragma unroll
    for (int kt = 0; kt < 2; kt++) {
      const int b0 = kt * 8;
      int w0 = cvtpk_bf16(s[b0 + 0], s[b0 + 1]);
      int w1 = cvtpk_bf16(s[b0 + 2], s[b0 + 3]);
      int w2 = cvtpk_bf16(s[b0 + 4], s[b0 + 5]);
      int w3 = cvtpk_bf16(s[b0 + 6], s[b0 + 7]);
      permswap(w0, w2);
      permswap(w1, w3);
      union { int i[4]; bf16x8 v; } u;
      u.i[0] = w0; u.i[1] = w1; u.i[2] = w2; u.i[3] = w3;
      pf[kt] = u.v;
    }
    // PV: O += P V over own keys (register V frags)
    #pragma unroll
    for (int nt = 0; nt < 4; nt++) {
      #pragma unroll
      for (int kt = 0; kt < 2; kt++)
        o[nt] = mfma32_bf(pf[kt], vfr[nt][kt], o[nt]);
    }
  }
  __syncthreads();   // loop exit sync before epilogue overwrites smem

  float lr = (lr0 + lr1) + (lr2 + lr3);
  // merge lh halves: lrw = this wave's full 32-key denominator for query l32
  float lrw = lr + __shfl_xor(lr, 32, 64);

  float* Cb = (float*)smem;                  // 2 heads x 32x128 fp32 = 32KB
  float* Lb = (float*)(smem + 32768);        // 128 denominator partials

  // phase 1: key-half ws==1 publishes raw O; all waves publish lrw
  if (ws == 1) {
    #pragma unroll
    for (int r = 0; r < 16; r++) {
      int m = (r & 3) + 8 * (r >> 2) + 4 * lh;
      #pragma unroll
      for (int nt = 0; nt < 4; nt++)
        Cb[hl * 4096 + m * 128 + nt * 32 + l32] = o[nt][r];
    }
  }
  if (lh == 0) Lb[ws * 64 + hl * 32 + l32] = lrw;
  __syncthreads();
  // phase 2: ws==0 merges halves and normalizes
  if (ws == 0) {
    #pragma unroll
    for (int r = 0; r < 16; r++) {
      int m = (r & 3) + 8 * (r >> 2) + 4 * lh;
      float inv = 1.0f / (Lb[hl * 32 + m] + Lb[64 + hl * 32 + m]);
      #pragma unroll
      for (int nt = 0; nt < 4; nt++)
        o[nt][r] = (o[nt][r] + Cb[hl * 4096 + m * 128 + nt * 32 + l32]) * inv;
    }
  }
  __syncthreads();
  // phase 3: head1 publishes normalized O1
  if (hl == 1 && ws == 0) {
    #pragma unroll
    for (int r = 0; r < 16; r++) {
      int m = (r & 3) + 8 * (r >> 2) + 4 * lh;
      #pragma unroll
      for (int nt = 0; nt < 4; nt++)
        Cb[4096 + m * 128 + nt * 32 + l32] = o[nt][r];
    }
  }
  __syncthreads();
  // phase 4: head0 does diff + rms-norm + store
  if (hl == 0 && ws == 0) {
    float ss[16];
    #pragma unroll
    for (int r = 0; r < 16; r++) {
      int m = (r & 3) + 8 * (r >> 2) + 4 * lh;
      ss[r] = 0.f;
      #pragma unroll
      for (int nt = 0; nt < 4; nt++) {
        float v = o[nt][r] - lam * Cb[4096 + m * 128 + nt * 32 + l32];
        o[nt][r] = v;
        ss[r] += v * v;
      }
    }
    #pragma unroll
    for (int r = 0; r < 16; r++) {
      ss[r] += __shfl_xor(ss[r], 1, 64);
      ss[r] += __shfl_xor(ss[r], 2, 64);
      ss[r] += __shfl_xor(ss[r], 4, 64);
      ss[r] += __shfl_xor(ss[r], 8, 64);
      ss[r] += __shfl_xor(ss[r], 16, 64);
      float rms = rsqrtf(ss[r] * (1.0f / 128.0f) + 1e-5f) * (1.0f - LAMBDA_INIT);
      int m = (r & 3) + 8 * (r >> 2) + 4 * lh;
      #pragma unroll
      for (int nt = 0; nt < 4; nt++)
        attn[(long)(t0 + m) * EMB + h * 128 + nt * 32 + l32] = (f16)(o[nt][r] * rms);
    }
  }
}

// =====================================================================
extern "C" void kernel_launch(void* const* d_in, const int* in_sizes, int n_in,
                              void* d_out, int out_size, void* d_ws, size_t ws_size,
                              hipStream_t stream)
{
  (void)in_sizes; (void)n_in; (void)out_size; (void)ws_size;
  const float* x   = (const float*)d_in[0];
  const float* Wq  = (const float*)d_in[1];
  const float* Wk  = (const float*)d_in[2];
  const float* Wv  = (const float*)d_in[3];
  const float* Wo  = (const float*)d_in[4];
  const float* lq1 = (const float*)d_in[5];
  const float* lk1 = (const float*)d_in[6];
  const float* lq2 = (const float*)d_in[7];
  const float* lk2 = (const float*)d_in[8];
  float* out = (float*)d_out;

  const size_t TM = (size_t)T_SEQ * EMB;  // 2M elems
  const size_t WM = (size_t)EMB * EMB;    // 1M elems
  bf16* vtws = (bf16*)d_ws;          // 4MB      @ 0
  f16*  aws  = (f16*)(vtws + TM);    // 4MB      @ 4MB
  f16*  xf   = aws  + TM;            // 4MB      @ 8MB
  f16*  wqf  = xf   + TM;            // 2MB      @ 12MB
  f16*  wkf  = wqf  + WM;            //          @ 14MB
  f16*  wvf  = wkf  + WM;            //          @ 16MB
  f16*  wof  = wvf  + WM;            //          @ 18MB
  f16*  qf   = wof  + WM;            // 4MB      @ 20MB
  f16*  kf   = qf   + TM;            // 4MB      @ 24MB

  // K-split partials REUSE dead regions (zero extra workspace):
  //  p0 (8MB fp32) over xf+wqf+wkf  — dead after qkv_gemm
  //  p1 (8MB fp32) over qf+kf       — dead after diff_attn
  float* p0 = (float*)xf;
  float* p1 = (float*)qf;

  convert_kernel<<<6144, 256, 0, stream>>>(x, Wq, Wk, Wv, Wo,
                                           xf, wqf, wkf, wvf, wof);
  qkv_gemm<<<768, 256, 0, stream>>>(xf, wqf, wkf, wvf, qf, kf, vtws);
  diff_attn<<<512, 256, 0, stream>>>(qf, kf, vtws, lq1, lk1, lq2, lk2, aws);
  out_gemm<<<512, 256, 0, stream>>>(aws, wof, p0, p1);
  add_out<<<2048, 256, 0, stream>>>(p0, p1, out);
}

// Round 14
// 169.924 us; speedup vs baseline: 1.2087x; 1.0195x over previous
//
#include <hip/hip_runtime.h>
#include <hip/hip_bf16.h>

typedef __hip_bfloat16 bf16;
typedef _Float16 f16;
typedef __attribute__((ext_vector_type(8))) __bf16 bf16x8;
typedef __attribute__((ext_vector_type(8))) _Float16 f16x8;
typedef __attribute__((ext_vector_type(4))) _Float16 f16x4;
typedef __attribute__((ext_vector_type(4))) float floatx4;
typedef __attribute__((ext_vector_type(16))) float floatx16;

#define T_SEQ 2048
#define EMB   1024
#define LAMBDA_INIT 0.35550906759096926f

// round-to-nearest-even fp32 -> bf16
__device__ __forceinline__ bf16 f2bf(float f) {
  unsigned u;
  __builtin_memcpy(&u, &f, 4);
  u += 0x7FFF + ((u >> 16) & 1);
  unsigned short h = (unsigned short)(u >> 16);
  bf16 r;
  __builtin_memcpy(&r, &h, 2);
  return r;
}

// v_cvt_pk_bf16_f32: d[15:0]=bf16(lo), d[31:16]=bf16(hi)
__device__ __forceinline__ int cvtpk_bf16(float lo, float hi) {
  int r;
  asm("v_cvt_pk_bf16_f32 %0, %1, %2" : "=v"(r) : "v"(lo), "v"(hi));
  return r;
}

// v_permlane32_swap_b32: swaps a's upper-32-lane half with b's lower half.
__device__ __forceinline__ void permswap(int& a, int& b) {
  asm volatile("v_permlane32_swap_b32 %0, %1" : "+v"(a), "+v"(b));
}

__device__ __forceinline__ void gl_lds16(const void* g, void* l) {
  __builtin_amdgcn_global_load_lds((const __attribute__((address_space(1))) void*)g,
                                   (__attribute__((address_space(3))) void*)l, 16, 0, 0);
}

__device__ __forceinline__ floatx4 mfma_h(f16x8 a, f16x8 b, floatx4 c) {
  return __builtin_amdgcn_mfma_f32_16x16x32_f16(a, b, c, 0, 0, 0);
}
__device__ __forceinline__ floatx16 mfma32_h(f16x8 a, f16x8 b, floatx16 c) {
  return __builtin_amdgcn_mfma_f32_32x32x16_f16(a, b, c, 0, 0, 0);
}
__device__ __forceinline__ floatx16 mfma32_bf(bf16x8 a, bf16x8 b, floatx16 c) {
  return __builtin_amdgcn_mfma_f32_32x32x16_bf16(a, b, c, 0, 0, 0);
}

// =====================================================================
// fp32 -> fp16 conversion for x, Wq, Wk, Wv, Wo.
// =====================================================================
__global__ __launch_bounds__(256) void convert_kernel(
    const float* __restrict__ x,  const float* __restrict__ wq,
    const float* __restrict__ wk, const float* __restrict__ wv,
    const float* __restrict__ wo,
    f16* __restrict__ xf, f16* __restrict__ wqf, f16* __restrict__ wkf,
    f16* __restrict__ wvf, f16* __restrict__ wof)
{
  int b = blockIdx.x;
  const float* src; f16* dst; long off;
  if      (b < 2048) { src = x;  dst = xf;  off = (long)b * 1024; }
  else if (b < 3072) { src = wq; dst = wqf; off = (long)(b - 2048) * 1024; }
  else if (b < 4096) { src = wk; dst = wkf; off = (long)(b - 3072) * 1024; }
  else if (b < 5120) { src = wv; dst = wvf; off = (long)(b - 4096) * 1024; }
  else               { src = wo; dst = wof; off = (long)(b - 5120) * 1024; }
  long i = off + threadIdx.x * 4;
  float4 v = *(const float4*)(src + i);
  f16x4 o;
  o.x = (f16)v.x; o.y = (f16)v.y; o.z = (f16)v.z; o.w = (f16)v.w;
  *(f16x4*)(dst + i) = o;
}

// =====================================================================
// fp16 NT GEMM, 64x128 tile, BK=64, 24KB LDS (r7-verified best-total
// config: 24KB footprint keeps block-level TLP, which measurement shows
// is the latency-hiding resource — deeper per-block schedules [r8 reg-
// staged, r9 direct, r10 depth-2 vmcnt, r11 XCD swizzle] were neutral
// to negative). Kld = row stride; Klen = K-extent (K-split support).
// MODE 2 = RoPE-Q epilogue (fold 0.125) -> fp16; MODE 3 = RoPE-K (inv)
// MODE 0 = bf16 out (V);  MODE 1 = fp32 out (output-projection partial)
// =====================================================================
template <int MODE>
__device__ __forceinline__ void gemm64x128_f16(
    const f16* __restrict__ A_, const f16* __restrict__ B_,
    void* C0v, int Kld, int Klen, int ldc, int m0, int n0, char* smem)
{
  f16* As = (f16*)smem;              // 64 x 64 swz (8 KB)
  f16* Bs = (f16*)(smem + 8192);     // 128 x 64 swz (16 KB)
  const int tid  = threadIdx.x;
  const int wave = tid >> 6, lane = tid & 63, quad = lane >> 4, l16 = lane & 15;
  const int mo = (wave & 1) << 5;
  const int no = (wave >> 1) << 6;

  floatx4 acc[2][4];
  #pragma unroll
  for (int i = 0; i < 2; i++)
    #pragma unroll
    for (int j = 0; j < 4; j++) { acc[i][j][0]=0.f; acc[i][j][1]=0.f; acc[i][j][2]=0.f; acc[i][j][3]=0.f; }

  const int srow = tid >> 3;
  const int ch   = (tid & 7) ^ (srow & 7);
  const long aoff = (long)(m0 + srow) * Kld + ch * 8;
  const long boff = (long)(n0 + srow) * Kld + ch * 8;
  const int wb = wave << 10;

  for (int k0 = 0; k0 < Klen; k0 += 64) {
    #pragma unroll
    for (int rr = 0; rr < 2; rr++)
      gl_lds16(A_ + aoff + k0 + (long)rr * 32 * Kld, smem + wb + rr * 4096);
    #pragma unroll
    for (int rr = 0; rr < 4; rr++)
      gl_lds16(B_ + boff + k0 + (long)rr * 32 * Kld, smem + 8192 + wb + rr * 4096);
    __syncthreads();
    #pragma unroll
    for (int kt = 0; kt < 2; kt++) {
      f16x8 a[2], b[4];
      #pragma unroll
      for (int i = 0; i < 2; i++) {
        int m = mo + i * 16 + l16;
        a[i] = *(const f16x8*)(As + m * 64 + ((((kt << 2) | quad) ^ (m & 7)) << 3));
      }
      #pragma unroll
      for (int j = 0; j < 4; j++) {
        int n = no + j * 16 + l16;
        b[j] = *(const f16x8*)(Bs + n * 64 + ((((kt << 2) | quad) ^ (n & 7)) << 3));
      }
      #pragma unroll
      for (int i = 0; i < 2; i++)
        #pragma unroll
        for (int j = 0; j < 4; j++)
          acc[i][j] = mfma_h(a[i], b[j], acc[i][j]);
    }
    __syncthreads();
  }

  if (MODE == 1) {
    #pragma unroll
    for (int i = 0; i < 2; i++)
      #pragma unroll
      for (int j = 0; j < 4; j++)
        #pragma unroll
        for (int r = 0; r < 4; r++) {
          int row = m0 + mo + i * 16 + quad * 4 + r;
          int col = n0 + no + j * 16 + l16;
          ((float*)C0v)[(long)row * ldc + col] = acc[i][j][r];
        }
  } else {
    unsigned short* E = (unsigned short*)smem;   // 64x128 2-byte = 16 KB
    #pragma unroll
    for (int i = 0; i < 2; i++)
      #pragma unroll
      for (int j = 0; j < 4; j++)
        #pragma unroll
        for (int r = 0; r < 4; r++) {
          int row = mo + i * 16 + quad * 4 + r;
          int col = no + j * 16 + l16;
          float v = acc[i][j][r];
          unsigned short bits;
          if (MODE == 0) {
            bf16 t = f2bf(v);
            __builtin_memcpy(&bits, &t, 2);
          } else {
            float p = __shfl_xor(v, 1, 64);
            int d = col & 63;
            float fr = (float)(m0 + row) * __expf((float)(d >> 1) * -0.28782313662425574f);
            float sn, cs;
            sincosf(fr, &sn, &cs);
            float rot = (col & 1) ? fmaf(v, cs, p * sn) : fmaf(v, cs, -p * sn);
            float power = (float)(m0 + row - 1024) * (1.0f / 512.0f);
            if (MODE == 3) power = -power;
            float sv = fmaf(2.0f, (float)(d & 31), 25.6f) * (1.0f / 89.6f);
            float s = __expf(power * __logf(sv));
            float ov = rot * s;
            if (MODE == 2) ov *= 0.125f;
            f16 t = (f16)ov;
            __builtin_memcpy(&bits, &t, 2);
          }
          E[row * 128 + col] = bits;
        }
    __syncthreads();
    const int rr0 = tid >> 4;
    const int c8  = (tid & 15) * 8;
    #pragma unroll
    for (int p2 = 0; p2 < 4; p2++) {
      int row = p2 * 16 + rr0;
      *(uint4*)((unsigned short*)C0v + (long)(m0 + row) * ldc + n0 + c8) =
          *(const uint4*)(E + row * 128 + c8);
    }
  }
}

__global__ __launch_bounds__(256) void qkv_gemm(
    const f16* __restrict__ xf,
    const f16* __restrict__ wqf, const f16* __restrict__ wkf,
    const f16* __restrict__ wvf,
    f16* __restrict__ qf, f16* __restrict__ kf, bf16* __restrict__ vt)
{
  __shared__ char smem[24576];
  int bid = blockIdx.x;
  if (bid < 256) {
    gemm64x128_f16<2>(xf, wqf, qf, 1024, 1024, 1024, (bid >> 3) * 64, (bid & 7) * 128, smem);
  } else if (bid < 512) {
    bid -= 256;
    gemm64x128_f16<3>(xf, wkf, kf, 1024, 1024, 1024, (bid >> 3) * 64, (bid & 7) * 128, smem);
  } else {
    bid -= 512;
    gemm64x128_f16<0>(wvf, xf, vt, 1024, 1024, 2048, (bid >> 4) * 64, (bid & 15) * 128, smem);
  }
}

// out_gemm K-split by 2: 512 blocks (2/CU) each accumulate a 64x128 fp32
// partial over half of K; add_out merges. (Fixes the 256-block = 1/CU
// starvation; measured −4.4 µs in r7.)
__global__ __launch_bounds__(256) void out_gemm(const f16* __restrict__ attn,
                                                const f16* __restrict__ Wo,
                                                float* __restrict__ p0,
                                                float* __restrict__ p1)
{
  __shared__ char smem[24576];
  int bid = blockIdx.x;
  const int kh = bid >> 8;       // K-half 0/1
  const int b  = bid & 255;
  float* pb = kh ? p1 : p0;
  gemm64x128_f16<1>(attn + kh * 512, Wo + kh * 512, pb, 1024, 512, 1024,
                    (b >> 3) * 64, (b & 7) * 128, smem);
}

__global__ __launch_bounds__(256) void add_out(const float* __restrict__ p0,
                                               const float* __restrict__ p1,
                                               float* __restrict__ out)
{
  long i = ((long)blockIdx.x * 256 + threadIdx.x) * 4;
  float4 a = *(const float4*)(p0 + i);
  float4 b = *(const float4*)(p1 + i);
  float4 c;
  c.x = a.x + b.x; c.y = a.y + b.y; c.z = a.z + b.z; c.w = a.w + b.w;
  *(float4*)(out + i) = c;
}

// =====================================================================
// Differential flash attention — register-staged single-barrier edition
// (round-5 structure) + T5 s_setprio around MFMA clusters. Mechanism
// check (m191 vs m190): 2 independent blocks/CU = phase-diverse waves
// on each CU -> scheduler has load-issuing vs MFMA-entering waves to
// arbitrate (m191 attn regime, +4-7%), unlike single-block lockstep
// GEMM (m190 null). Zero sync-structure change vs r12.
// =====================================================================
__global__ __launch_bounds__(256) void diff_attn(
    const f16* __restrict__ qf_, const f16* __restrict__ kf_,
    const bf16* __restrict__ vt,
    const float* __restrict__ lq1, const float* __restrict__ lk1,
    const float* __restrict__ lq2, const float* __restrict__ lk2,
    f16* __restrict__ attn)
{
  __shared__ char smem[65536];
  // buf b at b*32768: K0 @0 (8KB) | K1 @8192 (8KB) | V @16384 (16KB)
  const int tid  = threadIdx.x;
  const int wave = tid >> 6, lane = tid & 63;
  const int l32 = lane & 31, lh = lane >> 5;
  const int h  = blockIdx.x & 7;         // head pair — XCD-affine
  const int qb = blockIdx.x >> 3;        // q block 0..63 (32 rows each)
  const int hl = wave >> 1;              // head in pair
  const int ws = wave & 1;               // key-half of this wave
  const int hh = h * 2 + hl;
  const int t0 = qb * 32;

  float a1 = lq1[lane] * lk1[lane];
  float a2 = lq2[lane] * lk2[lane];
  #pragma unroll
  for (int off = 1; off < 64; off <<= 1) {
    a1 += __shfl_xor(a1, off, 64);
    a2 += __shfl_xor(a2, off, 64);
  }
  const float lam = __expf(a1) - __expf(a2) + LAMBDA_INIT;

  // Q B-frags (32 rows x 64 d): n=query=l32, k = kt*16 + lh*8 + j
  f16x8 qfr[4];
  {
    const f16* qrow = qf_ + (long)(t0 + l32) * EMB + hh * 64 + lh * 8;
    #pragma unroll
    for (int kt = 0; kt < 4; kt++) qfr[kt] = *(const f16x8*)(qrow + kt * 16);
  }

  floatx16 o[4];   // nt over Dv=128, un-normalized accumulation
  #pragma unroll
  for (int nt = 0; nt < 4; nt++)
    #pragma unroll
    for (int r = 0; r < 16; r++) o[nt][r] = 0.f;
  // denominator partials: 4-way tree to cut the serial add chain
  float lr0 = 0.f, lr1 = 0.f, lr2 = 0.f, lr3 = 0.f;

  // staging: waves 0,1 -> K0,K1; waves 2,3 -> V halves
  const int srow = lane >> 3;
  const int ch   = (lane & 7) ^ srow;
  const f16*  kgp = kf_ + (long)(h * 2 + ws) * 64 + (long)srow * EMB + ch * 8;
  const bf16* vgp = vt + (long)(h * 128 + (wave - 2) * 64 + srow) * T_SEQ + ch * 8;
  const int kofs = wave * 8192;                 // waves 0,1
  const int vofs = 16384 + (wave - 2) * 8192;   // waves 2,3

  // prologue: stage tile 0 into buffer 0
  if (wave < 2) {
    #pragma unroll
    for (int j = 0; j < 8; j++)
      gl_lds16(kgp + (long)j * 8 * EMB, smem + kofs + j * 1024);
  } else {
    #pragma unroll
    for (int j = 0; j < 8; j++)
      gl_lds16(vgp + (long)j * 8 * T_SEQ, smem + vofs + j * 1024);
  }

  for (int kb = 0; kb < T_SEQ; kb += 64) {
    const int cur = (kb >> 6) & 1;
    const char* sb = smem + cur * 32768;

    // own tile-i loads were issued a full iteration ago -> no stall
    asm volatile("s_waitcnt vmcnt(0)" ::: "memory");
    // all waves' tile-i loads landed; all waves left iter i-1
    asm volatile("s_barrier" ::: "memory");

    const f16*  Ks  = (const f16*)(sb + hl * 8192);
    const bf16* Vsb = (const bf16*)(sb + 16384);

    // ---- register staging: ALL ds_reads before any gl_lds issue ----
    f16x8 kfr[4];
    #pragma unroll
    for (int kt = 0; kt < 4; kt++) {
      int krow = ws * 32 + l32;
      int c = kt * 2 + lh;
      kfr[kt] = *(const f16x8*)(Ks + krow * 64 + ((c ^ (krow & 7)) << 3));
    }
    bf16x8 vfr[4][2];
    #pragma unroll
    for (int nt = 0; nt < 4; nt++) {
      #pragma unroll
      for (int kt = 0; kt < 2; kt++) {
        int vrow = nt * 32 + l32;
        int c = ws * 4 + kt * 2 + lh;
        vfr[nt][kt] = *(const bf16x8*)(Vsb + vrow * 64 + ((c ^ (vrow & 7)) << 3));
      }
    }

    // ---- prefetch issue (after all ds_reads in program order) ----
    if (kb + 64 < T_SEQ) {
      char* nb = smem + (cur ^ 1) * 32768;
      if (wave < 2) {
        #pragma unroll
        for (int j = 0; j < 8; j++)
          gl_lds16(kgp + (long)(kb + 64) * EMB + (long)j * 8 * EMB,
                   nb + kofs + j * 1024);
      } else {
        #pragma unroll
        for (int j = 0; j < 8; j++)
          gl_lds16(vgp + (kb + 64) + (long)j * 8 * T_SEQ,
                   nb + vofs + j * 1024);
      }
    }

    // ---- compute: pure registers from here ----
    // QK^T swapped: A=K (m=key=l32 of own half), B=Q (n=query=l32)
    floatx16 s;
    #pragma unroll
    for (int r = 0; r < 16; r++) s[r] = 0.f;
    __builtin_amdgcn_s_setprio(1);
    #pragma unroll
    for (int kt = 0; kt < 4; kt++)
      s = mfma32_h(kfr[kt], qfr[kt], s);
    __builtin_amdgcn_s_setprio(0);
    // static-offset softmax; denominator partials in a 4-way tree
    #pragma unroll
    for (int r = 0; r < 4; r++) {
      float p0 = __builtin_amdgcn_exp2f(
          fmaf(s[r], 1.4426950408889634f, -17.312340490667562f));
      float p1 = __builtin_amdgcn_exp2f(
          fmaf(s[r + 4], 1.4426950408889634f, -17.312340490667562f));
      float p2 = __builtin_amdgcn_exp2f(
          fmaf(s[r + 8], 1.4426950408889634f, -17.312340490667562f));
      float p3 = __builtin_amdgcn_exp2f(
          fmaf(s[r + 12], 1.4426950408889634f, -17.312340490667562f));
      s[r] = p0; s[r + 4] = p1; s[r + 8] = p2; s[r + 12] = p3;
      lr0 += p0; lr1 += p1; lr2 += p2; lr3 += p3;
    }
    // in-register P -> bf16 A-frags (cvt_pk + permlane32_swap)
    bf16x8 pf[2];
    #pragma unroll
    for (int kt = 0; kt < 2; kt++) {
      const int b0 = kt * 8;
      int w0 = cvtpk_bf16(s[b0 + 0], s[b0 + 1]);
      int w1 = cvtpk_bf16(s[b0 + 2], s[b0 + 3]);
      int w2 = cvtpk_bf16(s[b0 + 4], s[b0 + 5]);
      int w3 = cvtpk_bf16(s[b0 + 6], s[b0 + 7]);
      permswap(w0, w2);
      permswap(w1, w3);
      union { int i[4]; bf16x8 v; } u;
      u.i[0] = w0; u.i[1] = w1; u.i[2] = w2; u.i[3] = w3;
      pf[kt] = u.v;
    }
    // PV: O += P V over own keys (register V frags)
    __builtin_amdgcn_s_setprio(1);
    #pragma unroll
    for (int nt = 0; nt < 4; nt++) {
      #pragma unroll
      for (int kt = 0; kt < 2; kt++)
        o[nt] = mfma32_bf(pf[kt], vfr[nt][kt], o[nt]);
    }
    __builtin_amdgcn_s_setprio(0);
  }
  __syncthreads();   // loop exit sync before epilogue overwrites smem

  float lr = (lr0 + lr1) + (lr2 + lr3);
  // merge lh halves: lrw = this wave's full 32-key denominator for query l32
  float lrw = lr + __shfl_xor(lr, 32, 64);

  float* Cb = (float*)smem;                  // 2 heads x 32x128 fp32 = 32KB
  float* Lb = (float*)(smem + 32768);        // 128 denominator partials

  // phase 1: key-half ws==1 publishes raw O; all waves publish lrw
  if (ws == 1) {
    #pragma unroll
    for (int r = 0; r < 16; r++) {
      int m = (r & 3) + 8 * (r >> 2) + 4 * lh;
      #pragma unroll
      for (int nt = 0; nt < 4; nt++)
        Cb[hl * 4096 + m * 128 + nt * 32 + l32] = o[nt][r];
    }
  }
  if (lh == 0) Lb[ws * 64 + hl * 32 + l32] = lrw;
  __syncthreads();
  // phase 2: ws==0 merges halves and normalizes
  if (ws == 0) {
    #pragma unroll
    for (int r = 0; r < 16; r++) {
      int m = (r & 3) + 8 * (r >> 2) + 4 * lh;
      float inv = 1.0f / (Lb[hl * 32 + m] + Lb[64 + hl * 32 + m]);
      #pragma unroll
      for (int nt = 0; nt < 4; nt++)
        o[nt][r] = (o[nt][r] + Cb[hl * 4096 + m * 128 + nt * 32 + l32]) * inv;
    }
  }
  __syncthreads();
  // phase 3: head1 publishes normalized O1
  if (hl == 1 && ws == 0) {
    #pragma unroll
    for (int r = 0; r < 16; r++) {
      int m = (r & 3) + 8 * (r >> 2) + 4 * lh;
      #pragma unroll
      for (int nt = 0; nt < 4; nt++)
        Cb[4096 + m * 128 + nt * 32 + l32] = o[nt][r];
    }
  }
  __syncthreads();
  // phase 4: head0 does diff + rms-norm + store
  if (hl == 0 && ws == 0) {
    float ss[16];
    #pragma unroll
    for (int r = 0; r < 16; r++) {
      int m = (r & 3) + 8 * (r >> 2) + 4 * lh;
      ss[r] = 0.f;
      #pragma unroll
      for (int nt = 0; nt < 4; nt++) {
        float v = o[nt][r] - lam * Cb[4096 + m * 128 + nt * 32 + l32];
        o[nt][r] = v;
        ss[r] += v * v;
      }
    }
    #pragma unroll
    for (int r = 0; r < 16; r++) {
      ss[r] += __shfl_xor(ss[r], 1, 64);
      ss[r] += __shfl_xor(ss[r], 2, 64);
      ss[r] += __shfl_xor(ss[r], 4, 64);
      ss[r] += __shfl_xor(ss[r], 8, 64);
      ss[r] += __shfl_xor(ss[r], 16, 64);
      float rms = rsqrtf(ss[r] * (1.0f / 128.0f) + 1e-5f) * (1.0f - LAMBDA_INIT);
      int m = (r & 3) + 8 * (r >> 2) + 4 * lh;
      #pragma unroll
      for (int nt = 0; nt < 4; nt++)
        attn[(long)(t0 + m) * EMB + h * 128 + nt * 32 + l32] = (f16)(o[nt][r] * rms);
    }
  }
}

// =====================================================================
extern "C" void kernel_launch(void* const* d_in, const int* in_sizes, int n_in,
                              void* d_out, int out_size, void* d_ws, size_t ws_size,
                              hipStream_t stream)
{
  (void)in_sizes; (void)n_in; (void)out_size; (void)ws_size;
  const float* x   = (const float*)d_in[0];
  const float* Wq  = (const float*)d_in[1];
  const float* Wk  = (const float*)d_in[2];
  const float* Wv  = (const float*)d_in[3];
  const float* Wo  = (const float*)d_in[4];
  const float* lq1 = (const float*)d_in[5];
  const float* lk1 = (const float*)d_in[6];
  const float* lq2 = (const float*)d_in[7];
  const float* lk2 = (const float*)d_in[8];
  float* out = (float*)d_out;

  const size_t TM = (size_t)T_SEQ * EMB;  // 2M elems
  const size_t WM = (size_t)EMB * EMB;    // 1M elems
  bf16* vtws = (bf16*)d_ws;          // 4MB      @ 0
  f16*  aws  = (f16*)(vtws + TM);    // 4MB      @ 4MB
  f16*  xf   = aws  + TM;            // 4MB      @ 8MB
  f16*  wqf  = xf   + TM;            // 2MB      @ 12MB
  f16*  wkf  = wqf  + WM;            //          @ 14MB
  f16*  wvf  = wkf  + WM;            //          @ 16MB
  f16*  wof  = wvf  + WM;            //          @ 18MB
  f16*  qf   = wof  + WM;            // 4MB      @ 20MB
  f16*  kf   = qf   + TM;            // 4MB      @ 24MB

  // K-split partials REUSE dead regions (zero extra workspace):
  //  p0 (8MB fp32) over xf+wqf+wkf  — dead after qkv_gemm
  //  p1 (8MB fp32) over qf+kf       — dead after diff_attn
  float* p0 = (float*)xf;
  float* p1 = (float*)qf;

  convert_kernel<<<6144, 256, 0, stream>>>(x, Wq, Wk, Wv, Wo,
                                           xf, wqf, wkf, wvf, wof);
  qkv_gemm<<<768, 256, 0, stream>>>(xf, wqf, wkf, wvf, qf, kf, vtws);
  diff_attn<<<512, 256, 0, stream>>>(qf, kf, vtws, lq1, lk1, lq2, lk2, aws);
  out_gemm<<<512, 256, 0, stream>>>(aws, wof, p0, p1);
  add_out<<<2048, 256, 0, stream>>>(p0, p1, out);
}